// Round 11
// baseline (307.336 us; speedup 1.0000x reference)
//
#include <hip/hip_runtime.h>
#include <hip/hip_bf16.h>
#include <math.h>

#define Bq 4
#define Lq 2048
#define Dq 512
#define Hq 8
#define DKq 64
#define Uq 24
#define TSCAN 16
#define NTILE (Lq / TSCAN)   // 128
#define JCH 256              // softmax j-chunk
#define NCH (Lq / JCH)       // 8
#define TKCH 8               // top-k chunks per bh

typedef unsigned short ushort_t;
typedef unsigned long long u64;
typedef __attribute__((ext_vector_type(8))) short bfrag8;   // 8 bf16 (4 VGPRs)
typedef __attribute__((ext_vector_type(4))) float facc4;    // MFMA accumulator

__device__ inline ushort_t bf16_rne(float f) {
  unsigned u = __float_as_uint(f);
  u += 0x7FFF + ((u >> 16) & 1);
  return (ushort_t)(u >> 16);
}
__device__ inline float bf16f(ushort_t h) {
  return __uint_as_float(((unsigned)h) << 16);
}
// monotone float -> uint map (no NaNs in inputs)
__device__ inline unsigned fkey(float f) {
  unsigned u = __float_as_uint(f);
  return (u & 0x80000000u) ? ~u : (u | 0x80000000u);
}
// async global->LDS, 16B per lane (lds dest = wave base + lane*16)
__device__ __forceinline__ void gl2lds16(const void* g, void* l) {
  __builtin_amdgcn_global_load_lds(
      (const __attribute__((address_space(1))) unsigned*)g,
      (__attribute__((address_space(3))) unsigned*)l, 16, 0, 0);
}

// ---------------------------------------------------------------------------
// activations: one launch. y=0: q->hi/lo, y=1: k->hi/lo, y=2: v->hi
// ---------------------------------------------------------------------------
__global__ __launch_bounds__(256) void cast_all(
    const float* __restrict__ xq, const float* __restrict__ xk,
    const float* __restrict__ xv, ushort_t* __restrict__ qh,
    ushort_t* __restrict__ ql, ushort_t* __restrict__ kh,
    ushort_t* __restrict__ kl, ushort_t* __restrict__ vh) {
  int z = blockIdx.y;
  const float* x = z == 0 ? xq : (z == 1 ? xk : xv);
  ushort_t* hi = z == 0 ? qh : (z == 1 ? kh : vh);
  ushort_t* lo = z == 0 ? ql : kl;  // unused for z==2
  int t = blockIdx.x * 256 + threadIdx.x;
  float4 v = *(const float4*)&x[(size_t)t * 4];
  ushort_t h0 = bf16_rne(v.x), h1 = bf16_rne(v.y), h2 = bf16_rne(v.z),
           h3 = bf16_rne(v.w);
  ushort4 hh = {h0, h1, h2, h3};
  *(ushort4*)&hi[(size_t)t * 4] = hh;
  if (z < 2) {
    ushort4 ll = {bf16_rne(v.x - bf16f(h0)), bf16_rne(v.y - bf16f(h1)),
                  bf16_rne(v.z - bf16f(h2)), bf16_rne(v.w - bf16f(h3))};
    *(ushort4*)&lo[(size_t)t * 4] = ll;
  }
}

// ---------------------------------------------------------------------------
// All 4 weights: fp32 [k][n] -> transposed bf16 hi/lo [n][k] (one launch)
// ---------------------------------------------------------------------------
__global__ __launch_bounds__(256) void transpose_cast4(
    const float* __restrict__ W0, const float* __restrict__ W1,
    const float* __restrict__ W2, const float* __restrict__ W3,
    ushort_t* __restrict__ T0h, ushort_t* __restrict__ T0l,
    ushort_t* __restrict__ T1h, ushort_t* __restrict__ T1l,
    ushort_t* __restrict__ T2h, ushort_t* __restrict__ T3h) {
  __shared__ float tile[32][33];
  int z = blockIdx.z;
  const float* W = z == 0 ? W0 : (z == 1 ? W1 : (z == 2 ? W2 : W3));
  ushort_t* Th = z == 0 ? T0h : (z == 1 ? T1h : (z == 2 ? T2h : T3h));
  ushort_t* Tl = z == 0 ? T0l : (z == 1 ? T1l : nullptr);
  int k0 = blockIdx.x * 32, n0 = blockIdx.y * 32;
  int tx = threadIdx.x & 31, ty = threadIdx.x >> 5;  // ty 0..7
  for (int r = ty; r < 32; r += 8)
    tile[tx][r] = W[(size_t)(k0 + r) * 512 + n0 + tx];
  __syncthreads();
  for (int r = ty; r < 32; r += 8) {
    float v = tile[r][tx];
    ushort_t h = bf16_rne(v);
    Th[(size_t)(n0 + r) * 512 + k0 + tx] = h;
    if (Tl) Tl[(size_t)(n0 + r) * 512 + k0 + tx] = bf16_rne(v - bf16f(h));
  }
}

// ---------------------------------------------------------------------------
// Fused Q/K/V projection GEMM, 128x128 tile, 4 waves x (64x64).
// z=0: Q (split-bf16), z=1: K (split), z=2: V (plain hi).
// ---------------------------------------------------------------------------
__global__ __launch_bounds__(256) void gemm_qkv(
    const ushort_t* __restrict__ Aqh, const ushort_t* __restrict__ Aql,
    const ushort_t* __restrict__ Akh, const ushort_t* __restrict__ Akl,
    const ushort_t* __restrict__ Avh,
    const ushort_t* __restrict__ Wqh, const ushort_t* __restrict__ Wql,
    const ushort_t* __restrict__ Wkh, const ushort_t* __restrict__ Wkl,
    const ushort_t* __restrict__ Wvh,
    const float* __restrict__ bq, const float* __restrict__ bk,
    const float* __restrict__ bv,
    float* __restrict__ qo, float* __restrict__ ko, float* __restrict__ vo) {
  __shared__ ushort_t Ash[128][32], Asl[128][32];  // 8 KB each
  __shared__ ushort_t Bsh[128][32], Bsl[128][32];
  int which = blockIdx.z;
  const ushort_t* Ah = which == 0 ? Aqh : (which == 1 ? Akh : Avh);
  const ushort_t* Al = which == 0 ? Aql : Akl;  // unused for V
  const ushort_t* Bh = which == 0 ? Wqh : (which == 1 ? Wkh : Wvh);
  const ushort_t* Bl = which == 0 ? Wql : Wkl;
  const float* bias = which == 0 ? bq : (which == 1 ? bk : bv);
  float* C = which == 0 ? qo : (which == 1 ? ko : vo);
  const bool split = which < 2;

  int bm = blockIdx.x, bn = blockIdx.y;
  int tid = threadIdx.x;
  int wave = tid >> 6, lane = tid & 63;
  int wm = (wave & 1) * 64, wn = (wave >> 1) * 64;
  int quad = lane >> 4, lm = lane & 15;
  int srow = tid >> 2, skq = (tid & 3) * 8;   // staging slot
  facc4 acc[4][4] = {};

  for (int k0 = 0; k0 < 512; k0 += 32) {
#pragma unroll
    for (int p = 0; p < 2; ++p) {
      int row = srow + p * 64;
      size_t ga = (size_t)(bm * 128 + row) * 512 + k0 + skq;
      size_t gb = (size_t)(bn * 128 + row) * 512 + k0 + skq;
      gl2lds16(&Ah[ga], &Ash[row][skq]);
      gl2lds16(&Bh[gb], &Bsh[row][skq]);
      if (split) {
        gl2lds16(&Al[ga], &Asl[row][skq]);
        gl2lds16(&Bl[gb], &Bsl[row][skq]);
      }
    }
    __syncthreads();
    bfrag8 afh[4], afl[4], bfh[4], bfl[4];
#pragma unroll
    for (int mt = 0; mt < 4; ++mt) {
      afh[mt] = *(bfrag8*)&Ash[wm + mt * 16 + lm][quad * 8];
      if (split) afl[mt] = *(bfrag8*)&Asl[wm + mt * 16 + lm][quad * 8];
    }
#pragma unroll
    for (int nt = 0; nt < 4; ++nt) {
      bfh[nt] = *(bfrag8*)&Bsh[wn + nt * 16 + lm][quad * 8];
      if (split) bfl[nt] = *(bfrag8*)&Bsl[wn + nt * 16 + lm][quad * 8];
    }
#pragma unroll
    for (int mt = 0; mt < 4; ++mt)
#pragma unroll
      for (int nt = 0; nt < 4; ++nt) {
        facc4 a = acc[mt][nt];
        a = __builtin_amdgcn_mfma_f32_16x16x32_bf16(afh[mt], bfh[nt], a, 0, 0, 0);
        if (split) {
          a = __builtin_amdgcn_mfma_f32_16x16x32_bf16(afl[mt], bfh[nt], a, 0, 0, 0);
          a = __builtin_amdgcn_mfma_f32_16x16x32_bf16(afh[mt], bfl[nt], a, 0, 0, 0);
        }
        acc[mt][nt] = a;
      }
    __syncthreads();
  }
#pragma unroll
  for (int mt = 0; mt < 4; ++mt)
#pragma unroll
    for (int nt = 0; nt < 4; ++nt) {
      int col = bn * 128 + wn + nt * 16 + lm;
      float bv2 = bias[col];
#pragma unroll
      for (int r = 0; r < 4; ++r) {
        int row = bm * 128 + wm + mt * 16 + quad * 4 + r;
        C[(size_t)row * 512 + col] = acc[mt][nt][r] + bv2;
      }
    }
}

// ---------------------------------------------------------------------------
// bf16 MFMA GEMM (hi only, bf16 A): out projection, 128x128 tile, async stage
// ---------------------------------------------------------------------------
__global__ __launch_bounds__(256) void gemm_bf16(
    const ushort_t* __restrict__ A, const ushort_t* __restrict__ Bt,
    const float* __restrict__ bias, float* __restrict__ C) {
  __shared__ ushort_t As[128][32];
  __shared__ ushort_t Bs[128][32];
  int bm = blockIdx.x, bn = blockIdx.y;
  int tid = threadIdx.x;
  int wave = tid >> 6, lane = tid & 63;
  int wm = (wave & 1) * 64, wn = (wave >> 1) * 64;
  int quad = lane >> 4, lm = lane & 15;
  int srow = tid >> 2, skq = (tid & 3) * 8;
  facc4 acc[4][4] = {};

  for (int k0 = 0; k0 < 512; k0 += 32) {
#pragma unroll
    for (int p = 0; p < 2; ++p) {
      int row = srow + p * 64;
      gl2lds16(&A[(size_t)(bm * 128 + row) * 512 + k0 + skq], &As[row][skq]);
      gl2lds16(&Bt[(size_t)(bn * 128 + row) * 512 + k0 + skq], &Bs[row][skq]);
    }
    __syncthreads();
    bfrag8 af[4], bf[4];
#pragma unroll
    for (int mt = 0; mt < 4; ++mt)
      af[mt] = *(bfrag8*)&As[wm + mt * 16 + lm][quad * 8];
#pragma unroll
    for (int nt = 0; nt < 4; ++nt)
      bf[nt] = *(bfrag8*)&Bs[wn + nt * 16 + lm][quad * 8];
#pragma unroll
    for (int mt = 0; mt < 4; ++mt)
#pragma unroll
      for (int nt = 0; nt < 4; ++nt)
        acc[mt][nt] = __builtin_amdgcn_mfma_f32_16x16x32_bf16(
            af[mt], bf[nt], acc[mt][nt], 0, 0, 0);
    __syncthreads();
  }
#pragma unroll
  for (int mt = 0; mt < 4; ++mt)
#pragma unroll
    for (int nt = 0; nt < 4; ++nt) {
      int col = bn * 128 + wn + nt * 16 + lm;
      float bv = bias[col];
#pragma unroll
      for (int r = 0; r < 4; ++r) {
        int row = bm * 128 + wm + mt * 16 + quad * 4 + r;
        C[(size_t)row * 512 + col] = acc[mt][nt][r] + bv;
      }
    }
}

// ---------------------------------------------------------------------------
// m[b,h,l] = max_s(q.k_sample) - sum_s(q.k_sample)/L  (unchanged — bit-exact
// selection path)
// ---------------------------------------------------------------------------
__global__ __launch_bounds__(256) void compute_m(
    const float* __restrict__ q, const float* __restrict__ k,
    const int* __restrict__ idxs, float* __restrict__ m) {
  int wave = threadIdx.x >> 6, lane = threadIdx.x & 63;
  int lq = lane >> 4, dq = lane & 15;
  int slot = (blockIdx.x * 4 + wave) * 4 + lq;  // (b,h,l) flat
  int l = slot & (Lq - 1);
  int bh = slot >> 11;
  int h = bh & (Hq - 1), b = bh >> 3;
  float4 qv = *(const float4*)&q[((size_t)b * Lq + l) * Dq + h * DKq + dq * 4];
  const float* kb = &k[(size_t)b * Lq * Dq + h * DKq + dq * 4];
  const int* ib = &idxs[l * Uq];
  float mx = -INFINITY, sm = 0.f;
#pragma unroll
  for (int s = 0; s < Uq; ++s) {
    int j = ib[s];
    float4 kv = *(const float4*)&kb[(size_t)j * Dq];
    float p = qv.x * kv.x + qv.y * kv.y + qv.z * kv.z + qv.w * kv.w;
    p += __shfl_xor(p, 1, 64);
    p += __shfl_xor(p, 2, 64);
    p += __shfl_xor(p, 4, 64);
    p += __shfl_xor(p, 8, 64);
    mx = fmaxf(mx, p);
    sm += p;
  }
  if (dq == 0) m[slot] = mx - sm * (1.0f / Lq);
}

// ---------------------------------------------------------------------------
// top-24 per (b,h), two-stage bitonic on packed keys.
// stage2 also builds repl[] (indices already in LDS).
// ---------------------------------------------------------------------------
__device__ inline void bitonic256_desc(u64* s, int tid) {
  for (int k = 2; k <= 256; k <<= 1) {
    for (int j = k >> 1; j > 0; j >>= 1) {
      int p = tid ^ j;
      u64 mine = s[tid], other = s[p];
      u64 mx = mine > other ? mine : other;
      u64 mn = mine > other ? other : mine;
      bool dir = (tid & k) == 0;   // descending block
      bool lower = tid < p;
      u64 res = dir ? (lower ? mx : mn) : (lower ? mn : mx);
      __syncthreads();
      s[tid] = res;
      __syncthreads();
    }
  }
}

__global__ __launch_bounds__(256) void topk_stage1(
    const float* __restrict__ m, u64* __restrict__ cand) {
  __shared__ u64 s[256];
  int bh = blockIdx.x >> 3;      // 0..31
  int ch = blockIdx.x & 7;       // chunk 0..7
  int tid = threadIdx.x;
  int gidx = ch * 256 + tid;
  float v = m[(size_t)bh * Lq + gidx];
  s[tid] = ((u64)fkey(v) << 32) | (u64)(Lq - 1 - gidx);
  __syncthreads();
  bitonic256_desc(s, tid);
  if (tid < Uq) cand[((size_t)bh * TKCH + ch) * Uq + tid] = s[tid];
}

__global__ __launch_bounds__(256) void topk_stage2(
    const u64* __restrict__ cand, int* __restrict__ mtop,
    int* __restrict__ repl) {
  __shared__ u64 s[256];
  __shared__ int mt[Uq];
  int bh = blockIdx.x;
  int tid = threadIdx.x;
  s[tid] = (tid < TKCH * Uq) ? cand[(size_t)bh * TKCH * Uq + tid] : 0ull;
  __syncthreads();
  bitonic256_desc(s, tid);
  if (tid < Uq) {
    int idx = Lq - 1 - (int)(s[tid] & 0xFFFFFFFFull);
    mtop[bh * Uq + tid] = idx;
    mt[tid] = idx;
  }
  __syncthreads();
  for (int l = tid; l < Lq; l += 256) {
    int u = -1;
#pragma unroll
    for (int t = 0; t < Uq; ++t)
      if (mt[t] == l) u = t;
    repl[(size_t)bh * Lq + l] = u;
  }
}

// ---------------------------------------------------------------------------
// Fused scores + softmax + PV partials. Block = (j-chunk, bhu).
// Scores computed in-kernel (16 lanes per j, 4 j's per wave-iter) — no scg.
// ---------------------------------------------------------------------------
__global__ __launch_bounds__(256) void attn_partial(
    const float* __restrict__ q, const float* __restrict__ k,
    const float* __restrict__ v, const int* __restrict__ mtop,
    float* __restrict__ pmax, float* __restrict__ psum,
    float* __restrict__ pvp) {
  int blk = blockIdx.y;  // bh*U + u
  int jc = blockIdx.x;
  int bh = blk / Uq;
  int h = bh & (Hq - 1);
  int b = bh >> 3;
  int i0 = mtop[blk];
  int n = i0 + 1;          // causal bound
  int j0 = jc * JCH;
  if (j0 >= n) return;
  int cnt = min(JCH, n - j0);
  int tid = threadIdx.x, wave = tid >> 6, lane = tid & 63;
  int jq = lane >> 4, dq = lane & 15;
  __shared__ float es[JCH];      // scores -> exp values (in place)
  __shared__ float red[4][DKq];
  __shared__ float rr[4];
  const float scale = 0.044194173824159216f;  // 1/sqrt(512)

  // Phase A: scores. Wave w covers jloc in [w*64, w*64+64), 4 j's per iter.
  float4 qv = *(const float4*)&q[((size_t)b * Lq + i0) * Dq + h * DKq + dq * 4];
  const float* kb = &k[(size_t)b * Lq * Dq + h * DKq + dq * 4];
#pragma unroll 4
  for (int t = 0; t < 16; ++t) {
    int jloc = wave * 64 + t * 4 + jq;
    float4 kv = *(const float4*)&kb[(size_t)(j0 + jloc) * Dq];
    float p = qv.x * kv.x + qv.y * kv.y + qv.z * kv.z + qv.w * kv.w;
    p += __shfl_xor(p, 1, 64);
    p += __shfl_xor(p, 2, 64);
    p += __shfl_xor(p, 4, 64);
    p += __shfl_xor(p, 8, 64);
    if (dq == 0) es[jloc] = p * scale;
  }
  __syncthreads();

  // Phase B: chunk max
  float mx = (tid < cnt) ? es[tid] : -INFINITY;
#pragma unroll
  for (int off = 32; off; off >>= 1) mx = fmaxf(mx, __shfl_xor(mx, off, 64));
  if (lane == 0) rr[wave] = mx;
  __syncthreads();
  mx = fmaxf(fmaxf(rr[0], rr[1]), fmaxf(rr[2], rr[3]));
  __syncthreads();

  // Phase C: exp + sum
  float e = (tid < cnt) ? __expf(es[tid] - mx) : 0.f;
  __syncthreads();   // all reads of raw scores done before overwrite
  es[tid] = e;
  float sm = e;
#pragma unroll
  for (int off = 32; off; off >>= 1) sm += __shfl_xor(sm, off, 64);
  if (lane == 0) rr[wave] = sm;
  __syncthreads();

  // Phase D: PV partial
  float acc = 0.f;
  const float* vb = &v[((size_t)b * Lq + j0) * Dq + h * DKq + lane];
  int jlo = wave * 64;
  int jhi = min(jlo + 64, cnt);
#pragma unroll 4
  for (int j = jlo; j < jhi; ++j) acc += es[j] * vb[(size_t)j * Dq];
  red[wave][lane] = acc;
  __syncthreads();
  if (wave == 0) {
    if (lane == 0) {
      pmax[blk * NCH + jc] = mx;
      psum[blk * NCH + jc] = rr[0] + rr[1] + rr[2] + rr[3];
    }
    pvp[((size_t)blk * NCH + jc) * DKq + lane] =
        red[0][lane] + red[1][lane] + red[2][lane] + red[3][lane];
  }
}

// ---------------------------------------------------------------------------
// cumsum over L: tile sums, then build_context with inline exclusive prefix,
// inline softmax-combine for replaced rows, scatter, direct bf16 output.
// ---------------------------------------------------------------------------
__global__ __launch_bounds__(128) void tile_sum(const float* __restrict__ v,
                                                float* __restrict__ tsum) {
  int blk = blockIdx.x;  // b*NTILE + tile
  int tile = blk & (NTILE - 1);
  int b = blk >> 7;
  int d4 = threadIdx.x;  // 0..127 (float4 column slice)
  float4 s = {0.f, 0.f, 0.f, 0.f};
  const float* base = &v[((size_t)b * Lq + tile * TSCAN) * Dq + d4 * 4];
#pragma unroll
  for (int r = 0; r < TSCAN; ++r) {
    float4 x = *(const float4*)&base[(size_t)r * Dq];
    s.x += x.x; s.y += x.y; s.z += x.z; s.w += x.w;
  }
  *(float4*)&tsum[((size_t)b * NTILE + tile) * Dq + d4 * 4] = s;
}

__global__ __launch_bounds__(128) void build_context(
    const float* __restrict__ v, const float* __restrict__ tsum,
    const int* __restrict__ repl, const float* __restrict__ pmax,
    const float* __restrict__ psum, const float* __restrict__ pvp,
    ushort_t* __restrict__ ctxh) {
  int blk = blockIdx.x;  // b*NTILE + tile
  int tile = blk & (NTILE - 1);
  int b = blk >> 7;
  int d4 = threadIdx.x;          // float4 column slice
  int h = d4 >> 4;               // (d4*4)>>6
  // exclusive prefix over preceding tile sums (independent L2 loads)
  float4 run = {0.f, 0.f, 0.f, 0.f};
  const float* tb = &tsum[(size_t)b * NTILE * Dq + d4 * 4];
  for (int i = 0; i < tile; ++i) {
    float4 t = *(const float4*)&tb[(size_t)i * Dq];
    run.x += t.x; run.y += t.y; run.z += t.z; run.w += t.w;
  }
  const int* replb = &repl[(size_t)(b * Hq + h) * Lq + tile * TSCAN];
  const float* vb = &v[((size_t)b * Lq + tile * TSCAN) * Dq + d4 * 4];
  ushort_t* cb = &ctxh[((size_t)b * Lq + tile * TSCAN) * Dq + d4 * 4];
#pragma unroll
  for (int r = 0; r < TSCAN; ++r) {
    float4 x = *(const float4*)&vb[(size_t)r * Dq];
    run.x += x.x; run.y += x.y; run.z += x.z; run.w += x.w;
    int u = replb[r];
    float4 val = run;
    if (u >= 0) {
      // inline softmax combine: l == mtop[u]  =>  n = l+1
      int l = tile * TSCAN + r;
      int blku = (b * Hq + h) * Uq + u;
      int nc = (l + JCH) / JCH;  // ceil((l+1)/JCH)
      float gmax = -INFINITY;
      for (int c = 0; c < nc; ++c) gmax = fmaxf(gmax, pmax[blku * NCH + c]);
      float tot = 0.f;
      float4 acc = {0.f, 0.f, 0.f, 0.f};
      for (int c = 0; c < nc; ++c) {
        float wgt = __expf(pmax[blku * NCH + c] - gmax);
        tot += psum[blku * NCH + c] * wgt;
        float4 pv = *(const float4*)&pvp[((size_t)blku * NCH + c) * DKq +
                                         (d4 & 15) * 4];
        acc.x += pv.x * wgt; acc.y += pv.y * wgt;
        acc.z += pv.z * wgt; acc.w += pv.w * wgt;
      }
      float inv = 1.0f / tot;
      val.x = acc.x * inv; val.y = acc.y * inv;
      val.z = acc.z * inv; val.w = acc.w * inv;
    }
    ushort4 o = {bf16_rne(val.x), bf16_rne(val.y), bf16_rne(val.z),
                 bf16_rne(val.w)};
    *(ushort4*)&cb[(size_t)r * Dq] = o;
  }
}

// ---------------------------------------------------------------------------
extern "C" void kernel_launch(void* const* d_in, const int* in_sizes, int n_in,
                              void* d_out, int out_size, void* d_ws,
                              size_t ws_size, hipStream_t stream) {
  const float* queries = (const float*)d_in[0];
  const float* keys    = (const float*)d_in[1];
  const float* values  = (const float*)d_in[2];
  const int*   idxs    = (const int*)d_in[3];
  const float* Wq = (const float*)d_in[4];
  const float* bq = (const float*)d_in[5];
  const float* Wk = (const float*)d_in[6];
  const float* bk = (const float*)d_in[7];
  const float* Wv = (const float*)d_in[8];
  const float* bv = (const float*)d_in[9];
  const float* Wo = (const float*)d_in[10];
  const float* bo = (const float*)d_in[11];
  float* out = (float*)d_out;

  const size_t BLD = (size_t)Bq * Lq * Dq;  // 4,194,304
  char* w = (char*)d_ws;
  float* q    = (float*)w; w += BLD * 4;
  float* k    = (float*)w; w += BLD * 4;
  float* v    = (float*)w; w += BLD * 4;
  float* m    = (float*)w; w += (size_t)Bq * Hq * Lq * 4;
  float* tsum = (float*)w; w += (size_t)Bq * NTILE * Dq * 4;
  int* mtop   = (int*)w;   w += Bq * Hq * Uq * 4;
  int* repl   = (int*)w;   w += (size_t)Bq * Hq * Lq * 4;
  float* pmax = (float*)w; w += (size_t)Bq * Hq * Uq * NCH * 4;
  float* psum = (float*)w; w += (size_t)Bq * Hq * Uq * NCH * 4;
  float* pvp  = (float*)w; w += (size_t)Bq * Hq * Uq * NCH * DKq * 4;
  u64* cand   = (u64*)w;   w += (size_t)Bq * Hq * TKCH * Uq * 8;
  ushort_t* ctxh = (ushort_t*)w; w += BLD * 2;  // bf16 context
  ushort_t* Aqh = (ushort_t*)w; w += BLD * 2;   // pre-cast activations
  ushort_t* Aql = (ushort_t*)w; w += BLD * 2;
  ushort_t* Akh = (ushort_t*)w; w += BLD * 2;
  ushort_t* Akl = (ushort_t*)w; w += BLD * 2;
  ushort_t* Avh = (ushort_t*)w; w += BLD * 2;
  const size_t WSZ = 512 * 512;
  ushort_t* Wqh = (ushort_t*)w; w += WSZ * 2;
  ushort_t* Wql = (ushort_t*)w; w += WSZ * 2;
  ushort_t* Wkh = (ushort_t*)w; w += WSZ * 2;
  ushort_t* Wkl = (ushort_t*)w; w += WSZ * 2;
  ushort_t* Wvh = (ushort_t*)w; w += WSZ * 2;
  ushort_t* Woh = (ushort_t*)w; w += WSZ * 2;

  // weights: transpose + hi/lo cast, one launch
  {
    dim3 tgrid(16, 16, 4);
    transpose_cast4<<<tgrid, 256, 0, stream>>>(Wq, Wk, Wv, Wo, Wqh, Wql, Wkh,
                                               Wkl, Wvh, Woh);
  }

  // pre-cast activations, one launch (Q,K hi/lo; V hi)
  {
    dim3 cgrid(BLD / 4 / 256, 3);  // (4096, 3)
    cast_all<<<cgrid, 256, 0, stream>>>(queries, keys, values, Aqh, Aql, Akh,
                                        Akl, Avh);
  }

  // fused Q/K/V projections (128x128 tiles, async LDS staging)
  {
    dim3 ggrid(64, 4, 3);  // M=8192/128, N=512/128, z = Q/K/V
    gemm_qkv<<<ggrid, 256, 0, stream>>>(Aqh, Aql, Akh, Akl, Avh, Wqh, Wql,
                                        Wkh, Wkl, Wvh, bq, bk, bv, q, k, v);
  }

  // sparsity metric + top-k (two-stage bitonic; stage2 also builds repl)
  compute_m<<<(Bq * Hq * Lq) / 16, 256, 0, stream>>>(q, k, idxs, m);
  topk_stage1<<<Bq * Hq * TKCH, 256, 0, stream>>>(m, cand);
  topk_stage2<<<Bq * Hq, 256, 0, stream>>>(cand, mtop, repl);

  // attention on the top-24 rows: fused scores+softmax+PV partials
  {
    dim3 pgrid(NCH, Bq * Hq * Uq);  // (8, 768)
    attn_partial<<<pgrid, 256, 0, stream>>>(q, k, v, mtop, pmax, psum, pvp);
  }

  // cumsum context + scatter + inline combine, bf16 output
  tile_sum<<<Bq * NTILE, 128, 0, stream>>>(v, tsum);
  build_context<<<Bq * NTILE, 128, 0, stream>>>(v, tsum, repl, pmax, psum,
                                                pvp, ctxh);

  // output projection (plain bf16, 128x128 tiles, async LDS staging)
  {
    dim3 ggrid(64, 4);
    gemm_bf16<<<ggrid, 256, 0, stream>>>(ctxh, Woh, bo, out);
  }
}

// Round 12
// 298.410 us; speedup vs baseline: 1.0299x; 1.0299x over previous
//
#include <hip/hip_runtime.h>
#include <hip/hip_bf16.h>
#include <math.h>

#define Bq 4
#define Lq 2048
#define Dq 512
#define Hq 8
#define DKq 64
#define Uq 24
#define TSCAN 16
#define NTILE (Lq / TSCAN)   // 128
#define JCH 256              // softmax j-chunk
#define NCH (Lq / JCH)       // 8
#define TKCH 8               // top-k chunks per bh

typedef unsigned short ushort_t;
typedef unsigned long long u64;
typedef __attribute__((ext_vector_type(8))) short bfrag8;   // 8 bf16 (4 VGPRs)
typedef __attribute__((ext_vector_type(4))) float facc4;    // MFMA accumulator

__device__ inline ushort_t bf16_rne(float f) {
  unsigned u = __float_as_uint(f);
  u += 0x7FFF + ((u >> 16) & 1);
  return (ushort_t)(u >> 16);
}
__device__ inline float bf16f(ushort_t h) {
  return __uint_as_float(((unsigned)h) << 16);
}
// monotone float -> uint map (no NaNs in inputs)
__device__ inline unsigned fkey(float f) {
  unsigned u = __float_as_uint(f);
  return (u & 0x80000000u) ? ~u : (u | 0x80000000u);
}
// async global->LDS, 16B per lane (lds dest = wave base + lane*16)
__device__ __forceinline__ void gl2lds16(const void* g, void* l) {
  __builtin_amdgcn_global_load_lds(
      (const __attribute__((address_space(1))) unsigned*)g,
      (__attribute__((address_space(3))) unsigned*)l, 16, 0, 0);
}

// ---------------------------------------------------------------------------
// activations: one launch. y=0: q->hi/lo, y=1: k->hi/lo, y=2: v->hi
// ---------------------------------------------------------------------------
__global__ __launch_bounds__(256) void cast_all(
    const float* __restrict__ xq, const float* __restrict__ xk,
    const float* __restrict__ xv, ushort_t* __restrict__ qh,
    ushort_t* __restrict__ ql, ushort_t* __restrict__ kh,
    ushort_t* __restrict__ kl, ushort_t* __restrict__ vh) {
  int z = blockIdx.y;
  const float* x = z == 0 ? xq : (z == 1 ? xk : xv);
  ushort_t* hi = z == 0 ? qh : (z == 1 ? kh : vh);
  ushort_t* lo = z == 0 ? ql : kl;  // unused for z==2
  int t = blockIdx.x * 256 + threadIdx.x;
  float4 v = *(const float4*)&x[(size_t)t * 4];
  ushort_t h0 = bf16_rne(v.x), h1 = bf16_rne(v.y), h2 = bf16_rne(v.z),
           h3 = bf16_rne(v.w);
  ushort4 hh = {h0, h1, h2, h3};
  *(ushort4*)&hi[(size_t)t * 4] = hh;
  if (z < 2) {
    ushort4 ll = {bf16_rne(v.x - bf16f(h0)), bf16_rne(v.y - bf16f(h1)),
                  bf16_rne(v.z - bf16f(h2)), bf16_rne(v.w - bf16f(h3))};
    *(ushort4*)&lo[(size_t)t * 4] = ll;
  }
}

// ---------------------------------------------------------------------------
// All 4 weights: fp32 [k][n] -> transposed bf16 hi/lo [n][k] (one launch)
// ---------------------------------------------------------------------------
__global__ __launch_bounds__(256) void transpose_cast4(
    const float* __restrict__ W0, const float* __restrict__ W1,
    const float* __restrict__ W2, const float* __restrict__ W3,
    ushort_t* __restrict__ T0h, ushort_t* __restrict__ T0l,
    ushort_t* __restrict__ T1h, ushort_t* __restrict__ T1l,
    ushort_t* __restrict__ T2h, ushort_t* __restrict__ T3h) {
  __shared__ float tile[32][33];
  int z = blockIdx.z;
  const float* W = z == 0 ? W0 : (z == 1 ? W1 : (z == 2 ? W2 : W3));
  ushort_t* Th = z == 0 ? T0h : (z == 1 ? T1h : (z == 2 ? T2h : T3h));
  ushort_t* Tl = z == 0 ? T0l : (z == 1 ? T1l : nullptr);
  int k0 = blockIdx.x * 32, n0 = blockIdx.y * 32;
  int tx = threadIdx.x & 31, ty = threadIdx.x >> 5;  // ty 0..7
  for (int r = ty; r < 32; r += 8)
    tile[tx][r] = W[(size_t)(k0 + r) * 512 + n0 + tx];
  __syncthreads();
  for (int r = ty; r < 32; r += 8) {
    float v = tile[r][tx];
    ushort_t h = bf16_rne(v);
    Th[(size_t)(n0 + r) * 512 + k0 + tx] = h;
    if (Tl) Tl[(size_t)(n0 + r) * 512 + k0 + tx] = bf16_rne(v - bf16f(h));
  }
}

// ---------------------------------------------------------------------------
// Fused Q/K/V projection GEMM, 128x128 tile, 4 waves x (64x64).
// z=0: Q (split-bf16), z=1: K (split), z=2: V (plain hi).
// ---------------------------------------------------------------------------
__global__ __launch_bounds__(256) void gemm_qkv(
    const ushort_t* __restrict__ Aqh, const ushort_t* __restrict__ Aql,
    const ushort_t* __restrict__ Akh, const ushort_t* __restrict__ Akl,
    const ushort_t* __restrict__ Avh,
    const ushort_t* __restrict__ Wqh, const ushort_t* __restrict__ Wql,
    const ushort_t* __restrict__ Wkh, const ushort_t* __restrict__ Wkl,
    const ushort_t* __restrict__ Wvh,
    const float* __restrict__ bq, const float* __restrict__ bk,
    const float* __restrict__ bv,
    float* __restrict__ qo, float* __restrict__ ko, float* __restrict__ vo) {
  __shared__ ushort_t Ash[128][32], Asl[128][32];  // 8 KB each
  __shared__ ushort_t Bsh[128][32], Bsl[128][32];
  int which = blockIdx.z;
  const ushort_t* Ah = which == 0 ? Aqh : (which == 1 ? Akh : Avh);
  const ushort_t* Al = which == 0 ? Aql : Akl;  // unused for V
  const ushort_t* Bh = which == 0 ? Wqh : (which == 1 ? Wkh : Wvh);
  const ushort_t* Bl = which == 0 ? Wql : Wkl;
  const float* bias = which == 0 ? bq : (which == 1 ? bk : bv);
  float* C = which == 0 ? qo : (which == 1 ? ko : vo);
  const bool split = which < 2;

  int bm = blockIdx.x, bn = blockIdx.y;
  int tid = threadIdx.x;
  int wave = tid >> 6, lane = tid & 63;
  int wm = (wave & 1) * 64, wn = (wave >> 1) * 64;
  int quad = lane >> 4, lm = lane & 15;
  int srow = tid >> 2, skq = (tid & 3) * 8;   // staging slot
  facc4 acc[4][4] = {};

  for (int k0 = 0; k0 < 512; k0 += 32) {
#pragma unroll
    for (int p = 0; p < 2; ++p) {
      int row = srow + p * 64;
      size_t ga = (size_t)(bm * 128 + row) * 512 + k0 + skq;
      size_t gb = (size_t)(bn * 128 + row) * 512 + k0 + skq;
      gl2lds16(&Ah[ga], &Ash[row][skq]);
      gl2lds16(&Bh[gb], &Bsh[row][skq]);
      if (split) {
        gl2lds16(&Al[ga], &Asl[row][skq]);
        gl2lds16(&Bl[gb], &Bsl[row][skq]);
      }
    }
    __syncthreads();
    bfrag8 afh[4], afl[4], bfh[4], bfl[4];
#pragma unroll
    for (int mt = 0; mt < 4; ++mt) {
      afh[mt] = *(bfrag8*)&Ash[wm + mt * 16 + lm][quad * 8];
      if (split) afl[mt] = *(bfrag8*)&Asl[wm + mt * 16 + lm][quad * 8];
    }
#pragma unroll
    for (int nt = 0; nt < 4; ++nt) {
      bfh[nt] = *(bfrag8*)&Bsh[wn + nt * 16 + lm][quad * 8];
      if (split) bfl[nt] = *(bfrag8*)&Bsl[wn + nt * 16 + lm][quad * 8];
    }
#pragma unroll
    for (int mt = 0; mt < 4; ++mt)
#pragma unroll
      for (int nt = 0; nt < 4; ++nt) {
        facc4 a = acc[mt][nt];
        a = __builtin_amdgcn_mfma_f32_16x16x32_bf16(afh[mt], bfh[nt], a, 0, 0, 0);
        if (split) {
          a = __builtin_amdgcn_mfma_f32_16x16x32_bf16(afl[mt], bfh[nt], a, 0, 0, 0);
          a = __builtin_amdgcn_mfma_f32_16x16x32_bf16(afh[mt], bfl[nt], a, 0, 0, 0);
        }
        acc[mt][nt] = a;
      }
    __syncthreads();
  }
#pragma unroll
  for (int mt = 0; mt < 4; ++mt)
#pragma unroll
    for (int nt = 0; nt < 4; ++nt) {
      int col = bn * 128 + wn + nt * 16 + lm;
      float bv2 = bias[col];
#pragma unroll
      for (int r = 0; r < 4; ++r) {
        int row = bm * 128 + wm + mt * 16 + quad * 4 + r;
        C[(size_t)row * 512 + col] = acc[mt][nt][r] + bv2;
      }
    }
}

// ---------------------------------------------------------------------------
// bf16 MFMA GEMM (hi only, bf16 A): out projection, 128x128 tile, async stage
// ---------------------------------------------------------------------------
__global__ __launch_bounds__(256) void gemm_bf16(
    const ushort_t* __restrict__ A, const ushort_t* __restrict__ Bt,
    const float* __restrict__ bias, float* __restrict__ C) {
  __shared__ ushort_t As[128][32];
  __shared__ ushort_t Bs[128][32];
  int bm = blockIdx.x, bn = blockIdx.y;
  int tid = threadIdx.x;
  int wave = tid >> 6, lane = tid & 63;
  int wm = (wave & 1) * 64, wn = (wave >> 1) * 64;
  int quad = lane >> 4, lm = lane & 15;
  int srow = tid >> 2, skq = (tid & 3) * 8;
  facc4 acc[4][4] = {};

  for (int k0 = 0; k0 < 512; k0 += 32) {
#pragma unroll
    for (int p = 0; p < 2; ++p) {
      int row = srow + p * 64;
      gl2lds16(&A[(size_t)(bm * 128 + row) * 512 + k0 + skq], &As[row][skq]);
      gl2lds16(&Bt[(size_t)(bn * 128 + row) * 512 + k0 + skq], &Bs[row][skq]);
    }
    __syncthreads();
    bfrag8 af[4], bf[4];
#pragma unroll
    for (int mt = 0; mt < 4; ++mt)
      af[mt] = *(bfrag8*)&As[wm + mt * 16 + lm][quad * 8];
#pragma unroll
    for (int nt = 0; nt < 4; ++nt)
      bf[nt] = *(bfrag8*)&Bs[wn + nt * 16 + lm][quad * 8];
#pragma unroll
    for (int mt = 0; mt < 4; ++mt)
#pragma unroll
      for (int nt = 0; nt < 4; ++nt)
        acc[mt][nt] = __builtin_amdgcn_mfma_f32_16x16x32_bf16(
            af[mt], bf[nt], acc[mt][nt], 0, 0, 0);
    __syncthreads();
  }
#pragma unroll
  for (int mt = 0; mt < 4; ++mt)
#pragma unroll
    for (int nt = 0; nt < 4; ++nt) {
      int col = bn * 128 + wn + nt * 16 + lm;
      float bv = bias[col];
#pragma unroll
      for (int r = 0; r < 4; ++r) {
        int row = bm * 128 + wm + mt * 16 + quad * 4 + r;
        C[(size_t)row * 512 + col] = acc[mt][nt][r] + bv;
      }
    }
}

// ---------------------------------------------------------------------------
// m[b,h,l] = max_s(q.k_sample) - sum_s(q.k_sample)/L  (bit-exact selection)
// ---------------------------------------------------------------------------
__global__ __launch_bounds__(256) void compute_m(
    const float* __restrict__ q, const float* __restrict__ k,
    const int* __restrict__ idxs, float* __restrict__ m) {
  int wave = threadIdx.x >> 6, lane = threadIdx.x & 63;
  int lq = lane >> 4, dq = lane & 15;
  int slot = (blockIdx.x * 4 + wave) * 4 + lq;  // (b,h,l) flat
  int l = slot & (Lq - 1);
  int bh = slot >> 11;
  int h = bh & (Hq - 1), b = bh >> 3;
  float4 qv = *(const float4*)&q[((size_t)b * Lq + l) * Dq + h * DKq + dq * 4];
  const float* kb = &k[(size_t)b * Lq * Dq + h * DKq + dq * 4];
  const int* ib = &idxs[l * Uq];
  float mx = -INFINITY, sm = 0.f;
#pragma unroll
  for (int s = 0; s < Uq; ++s) {
    int j = ib[s];
    float4 kv = *(const float4*)&kb[(size_t)j * Dq];
    float p = qv.x * kv.x + qv.y * kv.y + qv.z * kv.z + qv.w * kv.w;
    p += __shfl_xor(p, 1, 64);
    p += __shfl_xor(p, 2, 64);
    p += __shfl_xor(p, 4, 64);
    p += __shfl_xor(p, 8, 64);
    mx = fmaxf(mx, p);
    sm += p;
  }
  if (dq == 0) m[slot] = mx - sm * (1.0f / Lq);
}

// ---------------------------------------------------------------------------
// top-24 per (b,h), two-stage bitonic on packed keys.
// stage2 also builds repl[] (indices already in LDS).
// ---------------------------------------------------------------------------
__device__ inline void bitonic256_desc(u64* s, int tid) {
  for (int k = 2; k <= 256; k <<= 1) {
    for (int j = k >> 1; j > 0; j >>= 1) {
      int p = tid ^ j;
      u64 mine = s[tid], other = s[p];
      u64 mx = mine > other ? mine : other;
      u64 mn = mine > other ? other : mine;
      bool dir = (tid & k) == 0;   // descending block
      bool lower = tid < p;
      u64 res = dir ? (lower ? mx : mn) : (lower ? mn : mx);
      __syncthreads();
      s[tid] = res;
      __syncthreads();
    }
  }
}

__global__ __launch_bounds__(256) void topk_stage1(
    const float* __restrict__ m, u64* __restrict__ cand) {
  __shared__ u64 s[256];
  int bh = blockIdx.x >> 3;      // 0..31
  int ch = blockIdx.x & 7;       // chunk 0..7
  int tid = threadIdx.x;
  int gidx = ch * 256 + tid;
  float v = m[(size_t)bh * Lq + gidx];
  s[tid] = ((u64)fkey(v) << 32) | (u64)(Lq - 1 - gidx);
  __syncthreads();
  bitonic256_desc(s, tid);
  if (tid < Uq) cand[((size_t)bh * TKCH + ch) * Uq + tid] = s[tid];
}

__global__ __launch_bounds__(256) void topk_stage2(
    const u64* __restrict__ cand, int* __restrict__ mtop,
    int* __restrict__ repl) {
  __shared__ u64 s[256];
  __shared__ int mt[Uq];
  int bh = blockIdx.x;
  int tid = threadIdx.x;
  s[tid] = (tid < TKCH * Uq) ? cand[(size_t)bh * TKCH * Uq + tid] : 0ull;
  __syncthreads();
  bitonic256_desc(s, tid);
  if (tid < Uq) {
    int idx = Lq - 1 - (int)(s[tid] & 0xFFFFFFFFull);
    mtop[bh * Uq + tid] = idx;
    mt[tid] = idx;
  }
  __syncthreads();
  for (int l = tid; l < Lq; l += 256) {
    int u = -1;
#pragma unroll
    for (int t = 0; t < Uq; ++t)
      if (mt[t] == l) u = t;
    repl[(size_t)bh * Lq + l] = u;
  }
}

// ---------------------------------------------------------------------------
// scores[bh][u][j] = (q[b,i0[u],h,:] . k[b,j,h,:]) / sqrt(D)
// LDS-staged, register-tiled 3u x 2j, k reused across all 24 u's.
// ---------------------------------------------------------------------------
#define JT 256
#define JS 64

__global__ __launch_bounds__(256) void scores_kernel(
    const float* __restrict__ q, const float* __restrict__ k,
    const int* __restrict__ mtop, float* __restrict__ scg) {
  __shared__ float qs[Uq][DKq + 1];
  __shared__ float ks[JS][DKq + 1];
  __shared__ int i0s[Uq];
  int bh = blockIdx.y;
  int jt = blockIdx.x;
  int h = bh & (Hq - 1);
  int b = bh >> 3;
  int tid = threadIdx.x;
  if (tid < Uq) i0s[tid] = mtop[bh * Uq + tid];
  __syncthreads();
  for (int s = tid; s < Uq * 16; s += 256) {
    int u = s >> 4, qd = (s & 15) * 4;
    float4 t = *(const float4*)&q[((size_t)b * Lq + i0s[u]) * Dq + h * DKq + qd];
    qs[u][qd] = t.x; qs[u][qd + 1] = t.y; qs[u][qd + 2] = t.z; qs[u][qd + 3] = t.w;
  }
  int jp = tid & 31;
  int ug = tid >> 5;
  const float scale = 0.044194173824159216f;  // 1/sqrt(512)
  for (int sub = 0; sub < JT / JS; ++sub) {
    int jbase = jt * JT + sub * JS;
    __syncthreads();
    for (int s = tid; s < JS * 16; s += 256) {
      int j = s >> 4, qd = (s & 15) * 4;
      float4 t = *(const float4*)&k[((size_t)b * Lq + jbase + j) * Dq + h * DKq + qd];
      ks[j][qd] = t.x; ks[j][qd + 1] = t.y; ks[j][qd + 2] = t.z; ks[j][qd + 3] = t.w;
    }
    __syncthreads();
    float acc[3][2] = {};
    int j0 = jp * 2, j1 = j0 + 1;
#pragma unroll 8
    for (int d = 0; d < DKq; ++d) {
      float k0 = ks[j0][d], k1 = ks[j1][d];
#pragma unroll
      for (int uu = 0; uu < 3; ++uu) {
        float qv = qs[ug * 3 + uu][d];
        acc[uu][0] += qv * k0;
        acc[uu][1] += qv * k1;
      }
    }
#pragma unroll
    for (int uu = 0; uu < 3; ++uu) {
      int u = ug * 3 + uu;
      scg[((size_t)(bh * Uq + u)) * Lq + jbase + j0] = acc[uu][0] * scale;
      scg[((size_t)(bh * Uq + u)) * Lq + jbase + j1] = acc[uu][1] * scale;
    }
  }
}

// ---------------------------------------------------------------------------
// softmax+PV partials over j-chunks of 256 (reads scg)
// ---------------------------------------------------------------------------
__global__ __launch_bounds__(256) void softmax_pv_partial(
    const float* __restrict__ scg, const float* __restrict__ v,
    const int* __restrict__ mtop, float* __restrict__ pmax,
    float* __restrict__ psum, float* __restrict__ pvp) {
  int blk = blockIdx.y;  // bh*U + u
  int jc = blockIdx.x;
  int bh = blk / Uq;
  int h = bh & (Hq - 1);
  int b = bh >> 3;
  int n = mtop[blk] + 1;   // causal bound
  int j0 = jc * JCH;
  if (j0 >= n) return;
  int cnt = min(JCH, n - j0);
  int tid = threadIdx.x, wave = tid >> 6, lane = tid & 63;
  __shared__ float es[JCH];
  __shared__ float red[4][DKq];
  __shared__ float rr[4];

  const float* row = &scg[(size_t)blk * Lq + j0];
  float mx = (tid < cnt) ? row[tid] : -INFINITY;
#pragma unroll
  for (int off = 32; off; off >>= 1) mx = fmaxf(mx, __shfl_xor(mx, off, 64));
  if (lane == 0) rr[wave] = mx;
  __syncthreads();
  mx = fmaxf(fmaxf(rr[0], rr[1]), fmaxf(rr[2], rr[3]));
  __syncthreads();

  float e = (tid < cnt) ? __expf(row[tid] - mx) : 0.f;
  es[tid] = e;
  float sm = e;
#pragma unroll
  for (int off = 32; off; off >>= 1) sm += __shfl_xor(sm, off, 64);
  if (lane == 0) rr[wave] = sm;
  __syncthreads();

  float acc = 0.f;
  const float* vb = &v[((size_t)b * Lq + j0) * Dq + h * DKq + lane];
  int jlo = wave * 64;
  int jhi = min(jlo + 64, cnt);
#pragma unroll 4
  for (int j = jlo; j < jhi; ++j) acc += es[j] * vb[(size_t)j * Dq];
  red[wave][lane] = acc;
  __syncthreads();
  if (wave == 0) {
    if (lane == 0) {
      pmax[blk * NCH + jc] = mx;
      psum[blk * NCH + jc] = rr[0] + rr[1] + rr[2] + rr[3];
    }
    pvp[((size_t)blk * NCH + jc) * DKq + lane] =
        red[0][lane] + red[1][lane] + red[2][lane] + red[3][lane];
  }
}

// ---------------------------------------------------------------------------
// cumsum over L: tile sums, then build_context with inline exclusive prefix,
// inline softmax-combine for replaced rows, scatter, direct bf16 output.
// ---------------------------------------------------------------------------
__global__ __launch_bounds__(128) void tile_sum(const float* __restrict__ v,
                                                float* __restrict__ tsum) {
  int blk = blockIdx.x;  // b*NTILE + tile
  int tile = blk & (NTILE - 1);
  int b = blk >> 7;
  int d4 = threadIdx.x;  // 0..127 (float4 column slice)
  float4 s = {0.f, 0.f, 0.f, 0.f};
  const float* base = &v[((size_t)b * Lq + tile * TSCAN) * Dq + d4 * 4];
#pragma unroll
  for (int r = 0; r < TSCAN; ++r) {
    float4 x = *(const float4*)&base[(size_t)r * Dq];
    s.x += x.x; s.y += x.y; s.z += x.z; s.w += x.w;
  }
  *(float4*)&tsum[((size_t)b * NTILE + tile) * Dq + d4 * 4] = s;
}

__global__ __launch_bounds__(128) void build_context(
    const float* __restrict__ v, const float* __restrict__ tsum,
    const int* __restrict__ repl, const float* __restrict__ pmax,
    const float* __restrict__ psum, const float* __restrict__ pvp,
    ushort_t* __restrict__ ctxh) {
  int blk = blockIdx.x;  // b*NTILE + tile
  int tile = blk & (NTILE - 1);
  int b = blk >> 7;
  int d4 = threadIdx.x;          // float4 column slice
  int h = d4 >> 4;               // (d4*4)>>6
  float4 run = {0.f, 0.f, 0.f, 0.f};
  const float* tb = &tsum[(size_t)b * NTILE * Dq + d4 * 4];
  for (int i = 0; i < tile; ++i) {
    float4 t = *(const float4*)&tb[(size_t)i * Dq];
    run.x += t.x; run.y += t.y; run.z += t.z; run.w += t.w;
  }
  const int* replb = &repl[(size_t)(b * Hq + h) * Lq + tile * TSCAN];
  const float* vb = &v[((size_t)b * Lq + tile * TSCAN) * Dq + d4 * 4];
  ushort_t* cb = &ctxh[((size_t)b * Lq + tile * TSCAN) * Dq + d4 * 4];
#pragma unroll
  for (int r = 0; r < TSCAN; ++r) {
    float4 x = *(const float4*)&vb[(size_t)r * Dq];
    run.x += x.x; run.y += x.y; run.z += x.z; run.w += x.w;
    int u = replb[r];
    float4 val = run;
    if (u >= 0) {
      // inline softmax combine: l == mtop[u]  =>  n = l+1
      int l = tile * TSCAN + r;
      int blku = (b * Hq + h) * Uq + u;
      int nc = (l + JCH) / JCH;  // ceil((l+1)/JCH)
      float gmax = -INFINITY;
      for (int c = 0; c < nc; ++c) gmax = fmaxf(gmax, pmax[blku * NCH + c]);
      float tot = 0.f;
      float4 acc = {0.f, 0.f, 0.f, 0.f};
      for (int c = 0; c < nc; ++c) {
        float wgt = __expf(pmax[blku * NCH + c] - gmax);
        tot += psum[blku * NCH + c] * wgt;
        float4 pv = *(const float4*)&pvp[((size_t)blku * NCH + c) * DKq +
                                         (d4 & 15) * 4];
        acc.x += pv.x * wgt; acc.y += pv.y * wgt;
        acc.z += pv.z * wgt; acc.w += pv.w * wgt;
      }
      float inv = 1.0f / tot;
      val.x = acc.x * inv; val.y = acc.y * inv;
      val.z = acc.z * inv; val.w = acc.w * inv;
    }
    ushort4 o = {bf16_rne(val.x), bf16_rne(val.y), bf16_rne(val.z),
                 bf16_rne(val.w)};
    *(ushort4*)&cb[(size_t)r * Dq] = o;
  }
}

// ---------------------------------------------------------------------------
extern "C" void kernel_launch(void* const* d_in, const int* in_sizes, int n_in,
                              void* d_out, int out_size, void* d_ws,
                              size_t ws_size, hipStream_t stream) {
  const float* queries = (const float*)d_in[0];
  const float* keys    = (const float*)d_in[1];
  const float* values  = (const float*)d_in[2];
  const int*   idxs    = (const int*)d_in[3];
  const float* Wq = (const float*)d_in[4];
  const float* bq = (const float*)d_in[5];
  const float* Wk = (const float*)d_in[6];
  const float* bk = (const float*)d_in[7];
  const float* Wv = (const float*)d_in[8];
  const float* bv = (const float*)d_in[9];
  const float* Wo = (const float*)d_in[10];
  const float* bo = (const float*)d_in[11];
  float* out = (float*)d_out;

  const size_t BLD = (size_t)Bq * Lq * Dq;  // 4,194,304
  char* w = (char*)d_ws;
  float* q    = (float*)w; w += BLD * 4;
  float* k    = (float*)w; w += BLD * 4;
  float* v    = (float*)w; w += BLD * 4;
  float* scg  = (float*)w; w += (size_t)Bq * Hq * Uq * Lq * 4;  // 6.3 MB
  float* m    = (float*)w; w += (size_t)Bq * Hq * Lq * 4;
  float* tsum = (float*)w; w += (size_t)Bq * NTILE * Dq * 4;
  int* mtop   = (int*)w;   w += Bq * Hq * Uq * 4;
  int* repl   = (int*)w;   w += (size_t)Bq * Hq * Lq * 4;
  float* pmax = (float*)w; w += (size_t)Bq * Hq * Uq * NCH * 4;
  float* psum = (float*)w; w += (size_t)Bq * Hq * Uq * NCH * 4;
  float* pvp  = (float*)w; w += (size_t)Bq * Hq * Uq * NCH * DKq * 4;
  u64* cand   = (u64*)w;   w += (size_t)Bq * Hq * TKCH * Uq * 8;
  ushort_t* ctxh = (ushort_t*)w; w += BLD * 2;  // bf16 context
  ushort_t* Aqh = (ushort_t*)w; w += BLD * 2;   // pre-cast activations
  ushort_t* Aql = (ushort_t*)w; w += BLD * 2;
  ushort_t* Akh = (ushort_t*)w; w += BLD * 2;
  ushort_t* Akl = (ushort_t*)w; w += BLD * 2;
  ushort_t* Avh = (ushort_t*)w; w += BLD * 2;
  const size_t WSZ = 512 * 512;
  ushort_t* Wqh = (ushort_t*)w; w += WSZ * 2;
  ushort_t* Wql = (ushort_t*)w; w += WSZ * 2;
  ushort_t* Wkh = (ushort_t*)w; w += WSZ * 2;
  ushort_t* Wkl = (ushort_t*)w; w += WSZ * 2;
  ushort_t* Wvh = (ushort_t*)w; w += WSZ * 2;
  ushort_t* Woh = (ushort_t*)w; w += WSZ * 2;

  // weights: transpose + hi/lo cast, one launch
  {
    dim3 tgrid(16, 16, 4);
    transpose_cast4<<<tgrid, 256, 0, stream>>>(Wq, Wk, Wv, Wo, Wqh, Wql, Wkh,
                                               Wkl, Wvh, Woh);
  }

  // pre-cast activations, one launch (Q,K hi/lo; V hi)
  {
    dim3 cgrid(BLD / 4 / 256, 3);  // (4096, 3)
    cast_all<<<cgrid, 256, 0, stream>>>(queries, keys, values, Aqh, Aql, Akh,
                                        Akl, Avh);
  }

  // fused Q/K/V projections (128x128 tiles, async LDS staging)
  {
    dim3 ggrid(64, 4, 3);  // M=8192/128, N=512/128, z = Q/K/V
    gemm_qkv<<<ggrid, 256, 0, stream>>>(Aqh, Aql, Akh, Akl, Avh, Wqh, Wql,
                                        Wkh, Wkl, Wvh, bq, bk, bv, q, k, v);
  }

  // sparsity metric + top-k (two-stage bitonic; stage2 also builds repl)
  compute_m<<<(Bq * Hq * Lq) / 16, 256, 0, stream>>>(q, k, idxs, m);
  topk_stage1<<<Bq * Hq * TKCH, 256, 0, stream>>>(m, cand);
  topk_stage2<<<Bq * Hq, 256, 0, stream>>>(cand, mtop, repl);

  // attention on the top-24 rows: scores (LDS-tiled) -> softmax+PV partials
  {
    dim3 sgrid(Lq / JT, Bq * Hq);  // (8, 32)
    scores_kernel<<<sgrid, 256, 0, stream>>>(q, k, mtop, scg);
  }
  {
    dim3 pgrid(NCH, Bq * Hq * Uq);  // (8, 768)
    softmax_pv_partial<<<pgrid, 256, 0, stream>>>(scg, v, mtop, pmax, psum, pvp);
  }

  // cumsum context + scatter + inline combine, bf16 output
  tile_sum<<<Bq * NTILE, 128, 0, stream>>>(v, tsum);
  build_context<<<Bq * NTILE, 128, 0, stream>>>(v, tsum, repl, pmax, psum,
                                                pvp, ctxh);

  // output projection (plain bf16, 128x128 tiles, async LDS staging)
  {
    dim3 ggrid(64, 4);
    gemm_bf16<<<ggrid, 256, 0, stream>>>(ctxh, Woh, bo, out);
  }
}

// Round 13
// 276.935 us; speedup vs baseline: 1.1098x; 1.0775x over previous
//
#include <hip/hip_runtime.h>
#include <hip/hip_bf16.h>
#include <math.h>

#define Bq 4
#define Lq 2048
#define Dq 512
#define Hq 8
#define DKq 64
#define Uq 24
#define TSCAN 16
#define NTILE (Lq / TSCAN)   // 128
#define NSUP 16              // supertiles (8 tiles each)
#define JCH 256              // softmax j-chunk
#define NCH (Lq / JCH)       // 8
#define TKCH 8               // top-k chunks per bh

typedef unsigned short ushort_t;
typedef unsigned long long u64;
typedef __attribute__((ext_vector_type(8))) short bfrag8;   // 8 bf16 (4 VGPRs)
typedef __attribute__((ext_vector_type(4))) float facc4;    // MFMA accumulator

__device__ inline ushort_t bf16_rne(float f) {
  unsigned u = __float_as_uint(f);
  u += 0x7FFF + ((u >> 16) & 1);
  return (ushort_t)(u >> 16);
}
__device__ inline float bf16f(ushort_t h) {
  return __uint_as_float(((unsigned)h) << 16);
}
// monotone float -> uint map (no NaNs in inputs)
__device__ inline unsigned fkey(float f) {
  unsigned u = __float_as_uint(f);
  return (u & 0x80000000u) ? ~u : (u | 0x80000000u);
}
// async global->LDS, 16B per lane (lds dest = wave base + lane*16)
__device__ __forceinline__ void gl2lds16(const void* g, void* l) {
  __builtin_amdgcn_global_load_lds(
      (const __attribute__((address_space(1))) unsigned*)g,
      (__attribute__((address_space(3))) unsigned*)l, 16, 0, 0);
}

// ---------------------------------------------------------------------------
// activations: one launch. y=0: q->hi/lo, y=1: k->hi/lo, y=2: v->hi
// ---------------------------------------------------------------------------
__global__ __launch_bounds__(256) void cast_all(
    const float* __restrict__ xq, const float* __restrict__ xk,
    const float* __restrict__ xv, ushort_t* __restrict__ qh,
    ushort_t* __restrict__ ql, ushort_t* __restrict__ kh,
    ushort_t* __restrict__ kl, ushort_t* __restrict__ vh) {
  int z = blockIdx.y;
  const float* x = z == 0 ? xq : (z == 1 ? xk : xv);
  ushort_t* hi = z == 0 ? qh : (z == 1 ? kh : vh);
  ushort_t* lo = z == 0 ? ql : kl;  // unused for z==2
  int t = blockIdx.x * 256 + threadIdx.x;
  float4 v = *(const float4*)&x[(size_t)t * 4];
  ushort_t h0 = bf16_rne(v.x), h1 = bf16_rne(v.y), h2 = bf16_rne(v.z),
           h3 = bf16_rne(v.w);
  ushort4 hh = {h0, h1, h2, h3};
  *(ushort4*)&hi[(size_t)t * 4] = hh;
  if (z < 2) {
    ushort4 ll = {bf16_rne(v.x - bf16f(h0)), bf16_rne(v.y - bf16f(h1)),
                  bf16_rne(v.z - bf16f(h2)), bf16_rne(v.w - bf16f(h3))};
    *(ushort4*)&lo[(size_t)t * 4] = ll;
  }
}

// ---------------------------------------------------------------------------
// All 4 weights: fp32 [k][n] -> transposed bf16 hi/lo [n][k] (one launch)
// ---------------------------------------------------------------------------
__global__ __launch_bounds__(256) void transpose_cast4(
    const float* __restrict__ W0, const float* __restrict__ W1,
    const float* __restrict__ W2, const float* __restrict__ W3,
    ushort_t* __restrict__ T0h, ushort_t* __restrict__ T0l,
    ushort_t* __restrict__ T1h, ushort_t* __restrict__ T1l,
    ushort_t* __restrict__ T2h, ushort_t* __restrict__ T3h) {
  __shared__ float tile[32][33];
  int z = blockIdx.z;
  const float* W = z == 0 ? W0 : (z == 1 ? W1 : (z == 2 ? W2 : W3));
  ushort_t* Th = z == 0 ? T0h : (z == 1 ? T1h : (z == 2 ? T2h : T3h));
  ushort_t* Tl = z == 0 ? T0l : (z == 1 ? T1l : nullptr);
  int k0 = blockIdx.x * 32, n0 = blockIdx.y * 32;
  int tx = threadIdx.x & 31, ty = threadIdx.x >> 5;  // ty 0..7
  for (int r = ty; r < 32; r += 8)
    tile[tx][r] = W[(size_t)(k0 + r) * 512 + n0 + tx];
  __syncthreads();
  for (int r = ty; r < 32; r += 8) {
    float v = tile[r][tx];
    ushort_t h = bf16_rne(v);
    Th[(size_t)(n0 + r) * 512 + k0 + tx] = h;
    if (Tl) Tl[(size_t)(n0 + r) * 512 + k0 + tx] = bf16_rne(v - bf16f(h));
  }
}

// ---------------------------------------------------------------------------
// Fused Q/K/V projection GEMM, 128x128 tile, 4 waves x (64x64).
// z=0: Q (split-bf16), z=1: K (split), z=2: V (plain hi).
// ---------------------------------------------------------------------------
__global__ __launch_bounds__(256) void gemm_qkv(
    const ushort_t* __restrict__ Aqh, const ushort_t* __restrict__ Aql,
    const ushort_t* __restrict__ Akh, const ushort_t* __restrict__ Akl,
    const ushort_t* __restrict__ Avh,
    const ushort_t* __restrict__ Wqh, const ushort_t* __restrict__ Wql,
    const ushort_t* __restrict__ Wkh, const ushort_t* __restrict__ Wkl,
    const ushort_t* __restrict__ Wvh,
    const float* __restrict__ bq, const float* __restrict__ bk,
    const float* __restrict__ bv,
    float* __restrict__ qo, float* __restrict__ ko, float* __restrict__ vo) {
  __shared__ ushort_t Ash[128][32], Asl[128][32];  // 8 KB each
  __shared__ ushort_t Bsh[128][32], Bsl[128][32];
  int which = blockIdx.z;
  const ushort_t* Ah = which == 0 ? Aqh : (which == 1 ? Akh : Avh);
  const ushort_t* Al = which == 0 ? Aql : Akl;  // unused for V
  const ushort_t* Bh = which == 0 ? Wqh : (which == 1 ? Wkh : Wvh);
  const ushort_t* Bl = which == 0 ? Wql : Wkl;
  const float* bias = which == 0 ? bq : (which == 1 ? bk : bv);
  float* C = which == 0 ? qo : (which == 1 ? ko : vo);
  const bool split = which < 2;

  int bm = blockIdx.x, bn = blockIdx.y;
  int tid = threadIdx.x;
  int wave = tid >> 6, lane = tid & 63;
  int wm = (wave & 1) * 64, wn = (wave >> 1) * 64;
  int quad = lane >> 4, lm = lane & 15;
  int srow = tid >> 2, skq = (tid & 3) * 8;   // staging slot
  facc4 acc[4][4] = {};

  for (int k0 = 0; k0 < 512; k0 += 32) {
#pragma unroll
    for (int p = 0; p < 2; ++p) {
      int row = srow + p * 64;
      size_t ga = (size_t)(bm * 128 + row) * 512 + k0 + skq;
      size_t gb = (size_t)(bn * 128 + row) * 512 + k0 + skq;
      gl2lds16(&Ah[ga], &Ash[row][skq]);
      gl2lds16(&Bh[gb], &Bsh[row][skq]);
      if (split) {
        gl2lds16(&Al[ga], &Asl[row][skq]);
        gl2lds16(&Bl[gb], &Bsl[row][skq]);
      }
    }
    __syncthreads();
    bfrag8 afh[4], afl[4], bfh[4], bfl[4];
#pragma unroll
    for (int mt = 0; mt < 4; ++mt) {
      afh[mt] = *(bfrag8*)&Ash[wm + mt * 16 + lm][quad * 8];
      if (split) afl[mt] = *(bfrag8*)&Asl[wm + mt * 16 + lm][quad * 8];
    }
#pragma unroll
    for (int nt = 0; nt < 4; ++nt) {
      bfh[nt] = *(bfrag8*)&Bsh[wn + nt * 16 + lm][quad * 8];
      if (split) bfl[nt] = *(bfrag8*)&Bsl[wn + nt * 16 + lm][quad * 8];
    }
#pragma unroll
    for (int mt = 0; mt < 4; ++mt)
#pragma unroll
      for (int nt = 0; nt < 4; ++nt) {
        facc4 a = acc[mt][nt];
        a = __builtin_amdgcn_mfma_f32_16x16x32_bf16(afh[mt], bfh[nt], a, 0, 0, 0);
        if (split) {
          a = __builtin_amdgcn_mfma_f32_16x16x32_bf16(afl[mt], bfh[nt], a, 0, 0, 0);
          a = __builtin_amdgcn_mfma_f32_16x16x32_bf16(afh[mt], bfl[nt], a, 0, 0, 0);
        }
        acc[mt][nt] = a;
      }
    __syncthreads();
  }
#pragma unroll
  for (int mt = 0; mt < 4; ++mt)
#pragma unroll
    for (int nt = 0; nt < 4; ++nt) {
      int col = bn * 128 + wn + nt * 16 + lm;
      float bv2 = bias[col];
#pragma unroll
      for (int r = 0; r < 4; ++r) {
        int row = bm * 128 + wm + mt * 16 + quad * 4 + r;
        C[(size_t)row * 512 + col] = acc[mt][nt][r] + bv2;
      }
    }
}

// ---------------------------------------------------------------------------
// bf16 MFMA GEMM (hi only, bf16 A): out projection, 128x128 tile, async stage
// ---------------------------------------------------------------------------
__global__ __launch_bounds__(256) void gemm_bf16(
    const ushort_t* __restrict__ A, const ushort_t* __restrict__ Bt,
    const float* __restrict__ bias, float* __restrict__ C) {
  __shared__ ushort_t As[128][32];
  __shared__ ushort_t Bs[128][32];
  int bm = blockIdx.x, bn = blockIdx.y;
  int tid = threadIdx.x;
  int wave = tid >> 6, lane = tid & 63;
  int wm = (wave & 1) * 64, wn = (wave >> 1) * 64;
  int quad = lane >> 4, lm = lane & 15;
  int srow = tid >> 2, skq = (tid & 3) * 8;
  facc4 acc[4][4] = {};

  for (int k0 = 0; k0 < 512; k0 += 32) {
#pragma unroll
    for (int p = 0; p < 2; ++p) {
      int row = srow + p * 64;
      gl2lds16(&A[(size_t)(bm * 128 + row) * 512 + k0 + skq], &As[row][skq]);
      gl2lds16(&Bt[(size_t)(bn * 128 + row) * 512 + k0 + skq], &Bs[row][skq]);
    }
    __syncthreads();
    bfrag8 af[4], bf[4];
#pragma unroll
    for (int mt = 0; mt < 4; ++mt)
      af[mt] = *(bfrag8*)&As[wm + mt * 16 + lm][quad * 8];
#pragma unroll
    for (int nt = 0; nt < 4; ++nt)
      bf[nt] = *(bfrag8*)&Bs[wn + nt * 16 + lm][quad * 8];
#pragma unroll
    for (int mt = 0; mt < 4; ++mt)
#pragma unroll
      for (int nt = 0; nt < 4; ++nt)
        acc[mt][nt] = __builtin_amdgcn_mfma_f32_16x16x32_bf16(
            af[mt], bf[nt], acc[mt][nt], 0, 0, 0);
    __syncthreads();
  }
#pragma unroll
  for (int mt = 0; mt < 4; ++mt)
#pragma unroll
    for (int nt = 0; nt < 4; ++nt) {
      int col = bn * 128 + wn + nt * 16 + lm;
      float bv = bias[col];
#pragma unroll
      for (int r = 0; r < 4; ++r) {
        int row = bm * 128 + wm + mt * 16 + quad * 4 + r;
        C[(size_t)row * 512 + col] = acc[mt][nt][r] + bv;
      }
    }
}

// ---------------------------------------------------------------------------
// m[b,h,l] = max_s(q.k_sample) - sum_s(q.k_sample)/L  (bit-exact selection)
// ---------------------------------------------------------------------------
__global__ __launch_bounds__(256) void compute_m(
    const float* __restrict__ q, const float* __restrict__ k,
    const int* __restrict__ idxs, float* __restrict__ m) {
  int wave = threadIdx.x >> 6, lane = threadIdx.x & 63;
  int lq = lane >> 4, dq = lane & 15;
  int slot = (blockIdx.x * 4 + wave) * 4 + lq;  // (b,h,l) flat
  int l = slot & (Lq - 1);
  int bh = slot >> 11;
  int h = bh & (Hq - 1), b = bh >> 3;
  float4 qv = *(const float4*)&q[((size_t)b * Lq + l) * Dq + h * DKq + dq * 4];
  const float* kb = &k[(size_t)b * Lq * Dq + h * DKq + dq * 4];
  const int* ib = &idxs[l * Uq];
  float mx = -INFINITY, sm = 0.f;
#pragma unroll
  for (int s = 0; s < Uq; ++s) {
    int j = ib[s];
    float4 kv = *(const float4*)&kb[(size_t)j * Dq];
    float p = qv.x * kv.x + qv.y * kv.y + qv.z * kv.z + qv.w * kv.w;
    p += __shfl_xor(p, 1, 64);
    p += __shfl_xor(p, 2, 64);
    p += __shfl_xor(p, 4, 64);
    p += __shfl_xor(p, 8, 64);
    mx = fmaxf(mx, p);
    sm += p;
  }
  if (dq == 0) m[slot] = mx - sm * (1.0f / Lq);
}

// ---------------------------------------------------------------------------
// top-24 per (b,h), two-stage bitonic on packed keys.
// stage2 also builds repl[] (indices already in LDS).
// ---------------------------------------------------------------------------
__device__ inline void bitonic256_desc(u64* s, int tid) {
  for (int k = 2; k <= 256; k <<= 1) {
    for (int j = k >> 1; j > 0; j >>= 1) {
      int p = tid ^ j;
      u64 mine = s[tid], other = s[p];
      u64 mx = mine > other ? mine : other;
      u64 mn = mine > other ? other : mine;
      bool dir = (tid & k) == 0;   // descending block
      bool lower = tid < p;
      u64 res = dir ? (lower ? mx : mn) : (lower ? mn : mx);
      __syncthreads();
      s[tid] = res;
      __syncthreads();
    }
  }
}

__global__ __launch_bounds__(256) void topk_stage1(
    const float* __restrict__ m, u64* __restrict__ cand) {
  __shared__ u64 s[256];
  int bh = blockIdx.x >> 3;      // 0..31
  int ch = blockIdx.x & 7;       // chunk 0..7
  int tid = threadIdx.x;
  int gidx = ch * 256 + tid;
  float v = m[(size_t)bh * Lq + gidx];
  s[tid] = ((u64)fkey(v) << 32) | (u64)(Lq - 1 - gidx);
  __syncthreads();
  bitonic256_desc(s, tid);
  if (tid < Uq) cand[((size_t)bh * TKCH + ch) * Uq + tid] = s[tid];
}

__global__ __launch_bounds__(256) void topk_stage2(
    const u64* __restrict__ cand, int* __restrict__ mtop,
    int* __restrict__ repl) {
  __shared__ u64 s[256];
  __shared__ int mt[Uq];
  int bh = blockIdx.x;
  int tid = threadIdx.x;
  s[tid] = (tid < TKCH * Uq) ? cand[(size_t)bh * TKCH * Uq + tid] : 0ull;
  __syncthreads();
  bitonic256_desc(s, tid);
  if (tid < Uq) {
    int idx = Lq - 1 - (int)(s[tid] & 0xFFFFFFFFull);
    mtop[bh * Uq + tid] = idx;
    mt[tid] = idx;
  }
  __syncthreads();
  for (int l = tid; l < Lq; l += 256) {
    int u = -1;
#pragma unroll
    for (int t = 0; t < Uq; ++t)
      if (mt[t] == l) u = t;
    repl[(size_t)bh * Lq + l] = u;
  }
}

// ---------------------------------------------------------------------------
// scores[bh][u][j] = (q[b,i0[u],h,:] . k[b,j,h,:]) / sqrt(D)
// LDS-staged, register-tiled 3u x 2j, k reused across all 24 u's.
// ---------------------------------------------------------------------------
#define JT 256
#define JS 64

__global__ __launch_bounds__(256) void scores_kernel(
    const float* __restrict__ q, const float* __restrict__ k,
    const int* __restrict__ mtop, float* __restrict__ scg) {
  __shared__ float qs[Uq][DKq + 1];
  __shared__ float ks[JS][DKq + 1];
  __shared__ int i0s[Uq];
  int bh = blockIdx.y;
  int jt = blockIdx.x;
  int h = bh & (Hq - 1);
  int b = bh >> 3;
  int tid = threadIdx.x;
  if (tid < Uq) i0s[tid] = mtop[bh * Uq + tid];
  __syncthreads();
  for (int s = tid; s < Uq * 16; s += 256) {
    int u = s >> 4, qd = (s & 15) * 4;
    float4 t = *(const float4*)&q[((size_t)b * Lq + i0s[u]) * Dq + h * DKq + qd];
    qs[u][qd] = t.x; qs[u][qd + 1] = t.y; qs[u][qd + 2] = t.z; qs[u][qd + 3] = t.w;
  }
  int jp = tid & 31;
  int ug = tid >> 5;
  const float scale = 0.044194173824159216f;  // 1/sqrt(512)
  for (int sub = 0; sub < JT / JS; ++sub) {
    int jbase = jt * JT + sub * JS;
    __syncthreads();
    for (int s = tid; s < JS * 16; s += 256) {
      int j = s >> 4, qd = (s & 15) * 4;
      float4 t = *(const float4*)&k[((size_t)b * Lq + jbase + j) * Dq + h * DKq + qd];
      ks[j][qd] = t.x; ks[j][qd + 1] = t.y; ks[j][qd + 2] = t.z; ks[j][qd + 3] = t.w;
    }
    __syncthreads();
    float acc[3][2] = {};
    int j0 = jp * 2, j1 = j0 + 1;
#pragma unroll 8
    for (int d = 0; d < DKq; ++d) {
      float k0 = ks[j0][d], k1 = ks[j1][d];
#pragma unroll
      for (int uu = 0; uu < 3; ++uu) {
        float qv = qs[ug * 3 + uu][d];
        acc[uu][0] += qv * k0;
        acc[uu][1] += qv * k1;
      }
    }
#pragma unroll
    for (int uu = 0; uu < 3; ++uu) {
      int u = ug * 3 + uu;
      scg[((size_t)(bh * Uq + u)) * Lq + jbase + j0] = acc[uu][0] * scale;
      scg[((size_t)(bh * Uq + u)) * Lq + jbase + j1] = acc[uu][1] * scale;
    }
  }
}

// ---------------------------------------------------------------------------
// softmax+PV partials over j-chunks of 256 (reads scg)
// ---------------------------------------------------------------------------
__global__ __launch_bounds__(256) void softmax_pv_partial(
    const float* __restrict__ scg, const float* __restrict__ v,
    const int* __restrict__ mtop, float* __restrict__ pmax,
    float* __restrict__ psum, float* __restrict__ pvp) {
  int blk = blockIdx.y;  // bh*U + u
  int jc = blockIdx.x;
  int bh = blk / Uq;
  int h = bh & (Hq - 1);
  int b = bh >> 3;
  int n = mtop[blk] + 1;   // causal bound
  int j0 = jc * JCH;
  if (j0 >= n) return;
  int cnt = min(JCH, n - j0);
  int tid = threadIdx.x, wave = tid >> 6, lane = tid & 63;
  __shared__ float es[JCH];
  __shared__ float red[4][DKq];
  __shared__ float rr[4];

  const float* row = &scg[(size_t)blk * Lq + j0];
  float mx = (tid < cnt) ? row[tid] : -INFINITY;
#pragma unroll
  for (int off = 32; off; off >>= 1) mx = fmaxf(mx, __shfl_xor(mx, off, 64));
  if (lane == 0) rr[wave] = mx;
  __syncthreads();
  mx = fmaxf(fmaxf(rr[0], rr[1]), fmaxf(rr[2], rr[3]));
  __syncthreads();

  float e = (tid < cnt) ? __expf(row[tid] - mx) : 0.f;
  es[tid] = e;
  float sm = e;
#pragma unroll
  for (int off = 32; off; off >>= 1) sm += __shfl_xor(sm, off, 64);
  if (lane == 0) rr[wave] = sm;
  __syncthreads();

  float acc = 0.f;
  const float* vb = &v[((size_t)b * Lq + j0) * Dq + h * DKq + lane];
  int jlo = wave * 64;
  int jhi = min(jlo + 64, cnt);
#pragma unroll 4
  for (int j = jlo; j < jhi; ++j) acc += es[j] * vb[(size_t)j * Dq];
  red[wave][lane] = acc;
  __syncthreads();
  if (wave == 0) {
    if (lane == 0) {
      pmax[blk * NCH + jc] = mx;
      psum[blk * NCH + jc] = rr[0] + rr[1] + rr[2] + rr[3];
    }
    pvp[((size_t)blk * NCH + jc) * DKq + lane] =
        red[0][lane] + red[1][lane] + red[2][lane] + red[3][lane];
  }
}

// ---------------------------------------------------------------------------
// cumsum over L: tile sums (16 rows), supertile sums (8 tiles), then
// build_context with two-level prefix (<=22 loads), inline combine, bf16 out.
// ---------------------------------------------------------------------------
__global__ __launch_bounds__(128) void tile_sum(const float* __restrict__ v,
                                                float* __restrict__ tsum) {
  int blk = blockIdx.x;  // b*NTILE + tile
  int tile = blk & (NTILE - 1);
  int b = blk >> 7;
  int d4 = threadIdx.x;  // 0..127 (float4 column slice)
  float4 s = {0.f, 0.f, 0.f, 0.f};
  const float* base = &v[((size_t)b * Lq + tile * TSCAN) * Dq + d4 * 4];
#pragma unroll
  for (int r = 0; r < TSCAN; ++r) {
    float4 x = *(const float4*)&base[(size_t)r * Dq];
    s.x += x.x; s.y += x.y; s.z += x.z; s.w += x.w;
  }
  *(float4*)&tsum[((size_t)b * NTILE + tile) * Dq + d4 * 4] = s;
}

__global__ __launch_bounds__(128) void stile_sum(
    const float* __restrict__ tsum, float* __restrict__ stsum) {
  int blk = blockIdx.x;  // b*NSUP + s
  int s = blk & (NSUP - 1);
  int b = blk >> 4;
  int d4 = threadIdx.x;
  float4 acc = {0.f, 0.f, 0.f, 0.f};
  const float* tb = &tsum[((size_t)b * NTILE + s * 8) * Dq + d4 * 4];
#pragma unroll
  for (int i = 0; i < 8; ++i) {
    float4 t = *(const float4*)&tb[(size_t)i * Dq];
    acc.x += t.x; acc.y += t.y; acc.z += t.z; acc.w += t.w;
  }
  *(float4*)&stsum[((size_t)b * NSUP + s) * Dq + d4 * 4] = acc;
}

__global__ __launch_bounds__(128) void build_context(
    const float* __restrict__ v, const float* __restrict__ tsum,
    const float* __restrict__ stsum, const int* __restrict__ repl,
    const float* __restrict__ pmax, const float* __restrict__ psum,
    const float* __restrict__ pvp, ushort_t* __restrict__ ctxh) {
  int blk = blockIdx.x;  // b*NTILE + tile
  int tile = blk & (NTILE - 1);
  int b = blk >> 7;
  int d4 = threadIdx.x;          // float4 column slice
  int h = d4 >> 4;               // (d4*4)>>6
  // two-level exclusive prefix: full supertiles + remaining tiles
  int sup = tile >> 3;
  float4 run = {0.f, 0.f, 0.f, 0.f};
  const float* sb = &stsum[(size_t)b * NSUP * Dq + d4 * 4];
  for (int s = 0; s < sup; ++s) {
    float4 t = *(const float4*)&sb[(size_t)s * Dq];
    run.x += t.x; run.y += t.y; run.z += t.z; run.w += t.w;
  }
  const float* tb = &tsum[((size_t)b * NTILE + sup * 8) * Dq + d4 * 4];
  int rem = tile & 7;
  for (int i = 0; i < rem; ++i) {
    float4 t = *(const float4*)&tb[(size_t)i * Dq];
    run.x += t.x; run.y += t.y; run.z += t.z; run.w += t.w;
  }
  const int* replb = &repl[(size_t)(b * Hq + h) * Lq + tile * TSCAN];
  const float* vb = &v[((size_t)b * Lq + tile * TSCAN) * Dq + d4 * 4];
  ushort_t* cb = &ctxh[((size_t)b * Lq + tile * TSCAN) * Dq + d4 * 4];
#pragma unroll
  for (int r = 0; r < TSCAN; ++r) {
    float4 x = *(const float4*)&vb[(size_t)r * Dq];
    run.x += x.x; run.y += x.y; run.z += x.z; run.w += x.w;
    int u = replb[r];
    float4 val = run;
    if (u >= 0) {
      // inline softmax combine: l == mtop[u]  =>  n = l+1
      int l = tile * TSCAN + r;
      int blku = (b * Hq + h) * Uq + u;
      int nc = (l + JCH) / JCH;  // ceil((l+1)/JCH)
      float gmax = -INFINITY;
      for (int c = 0; c < nc; ++c) gmax = fmaxf(gmax, pmax[blku * NCH + c]);
      float tot = 0.f;
      float4 acc = {0.f, 0.f, 0.f, 0.f};
      for (int c = 0; c < nc; ++c) {
        float wgt = __expf(pmax[blku * NCH + c] - gmax);
        tot += psum[blku * NCH + c] * wgt;
        float4 pv = *(const float4*)&pvp[((size_t)blku * NCH + c) * DKq +
                                         (d4 & 15) * 4];
        acc.x += pv.x * wgt; acc.y += pv.y * wgt;
        acc.z += pv.z * wgt; acc.w += pv.w * wgt;
      }
      float inv = 1.0f / tot;
      val.x = acc.x * inv; val.y = acc.y * inv;
      val.z = acc.z * inv; val.w = acc.w * inv;
    }
    ushort4 o = {bf16_rne(val.x), bf16_rne(val.y), bf16_rne(val.z),
                 bf16_rne(val.w)};
    *(ushort4*)&cb[(size_t)r * Dq] = o;
  }
}

// ---------------------------------------------------------------------------
extern "C" void kernel_launch(void* const* d_in, const int* in_sizes, int n_in,
                              void* d_out, int out_size, void* d_ws,
                              size_t ws_size, hipStream_t stream) {
  const float* queries = (const float*)d_in[0];
  const float* keys    = (const float*)d_in[1];
  const float* values  = (const float*)d_in[2];
  const int*   idxs    = (const int*)d_in[3];
  const float* Wq = (const float*)d_in[4];
  const float* bq = (const float*)d_in[5];
  const float* Wk = (const float*)d_in[6];
  const float* bk = (const float*)d_in[7];
  const float* Wv = (const float*)d_in[8];
  const float* bv = (const float*)d_in[9];
  const float* Wo = (const float*)d_in[10];
  const float* bo = (const float*)d_in[11];
  float* out = (float*)d_out;

  const size_t BLD = (size_t)Bq * Lq * Dq;  // 4,194,304
  char* w = (char*)d_ws;
  float* q    = (float*)w; w += BLD * 4;
  float* k    = (float*)w; w += BLD * 4;
  float* v    = (float*)w; w += BLD * 4;
  float* scg  = (float*)w; w += (size_t)Bq * Hq * Uq * Lq * 4;  // 6.3 MB
  float* m    = (float*)w; w += (size_t)Bq * Hq * Lq * 4;
  float* tsum = (float*)w; w += (size_t)Bq * NTILE * Dq * 4;
  float* stsum= (float*)w; w += (size_t)Bq * NSUP * Dq * 4;
  int* mtop   = (int*)w;   w += Bq * Hq * Uq * 4;
  int* repl   = (int*)w;   w += (size_t)Bq * Hq * Lq * 4;
  float* pmax = (float*)w; w += (size_t)Bq * Hq * Uq * NCH * 4;
  float* psum = (float*)w; w += (size_t)Bq * Hq * Uq * NCH * 4;
  float* pvp  = (float*)w; w += (size_t)Bq * Hq * Uq * NCH * DKq * 4;
  u64* cand   = (u64*)w;   w += (size_t)Bq * Hq * TKCH * Uq * 8;
  ushort_t* ctxh = (ushort_t*)w; w += BLD * 2;  // bf16 context
  ushort_t* Aqh = (ushort_t*)w; w += BLD * 2;   // pre-cast activations
  ushort_t* Aql = (ushort_t*)w; w += BLD * 2;
  ushort_t* Akh = (ushort_t*)w; w += BLD * 2;
  ushort_t* Akl = (ushort_t*)w; w += BLD * 2;
  ushort_t* Avh = (ushort_t*)w; w += BLD * 2;
  const size_t WSZ = 512 * 512;
  ushort_t* Wqh = (ushort_t*)w; w += WSZ * 2;
  ushort_t* Wql = (ushort_t*)w; w += WSZ * 2;
  ushort_t* Wkh = (ushort_t*)w; w += WSZ * 2;
  ushort_t* Wkl = (ushort_t*)w; w += WSZ * 2;
  ushort_t* Wvh = (ushort_t*)w; w += WSZ * 2;
  ushort_t* Woh = (ushort_t*)w; w += WSZ * 2;

  // weights: transpose + hi/lo cast, one launch
  {
    dim3 tgrid(16, 16, 4);
    transpose_cast4<<<tgrid, 256, 0, stream>>>(Wq, Wk, Wv, Wo, Wqh, Wql, Wkh,
                                               Wkl, Wvh, Woh);
  }

  // pre-cast activations, one launch (Q,K hi/lo; V hi)
  {
    dim3 cgrid(BLD / 4 / 256, 3);  // (4096, 3)
    cast_all<<<cgrid, 256, 0, stream>>>(queries, keys, values, Aqh, Aql, Akh,
                                        Akl, Avh);
  }

  // fused Q/K/V projections (128x128 tiles, async LDS staging)
  {
    dim3 ggrid(64, 4, 3);  // M=8192/128, N=512/128, z = Q/K/V
    gemm_qkv<<<ggrid, 256, 0, stream>>>(Aqh, Aql, Akh, Akl, Avh, Wqh, Wql,
                                        Wkh, Wkl, Wvh, bq, bk, bv, q, k, v);
  }

  // sparsity metric + top-k (two-stage bitonic; stage2 also builds repl)
  compute_m<<<(Bq * Hq * Lq) / 16, 256, 0, stream>>>(q, k, idxs, m);
  topk_stage1<<<Bq * Hq * TKCH, 256, 0, stream>>>(m, cand);
  topk_stage2<<<Bq * Hq, 256, 0, stream>>>(cand, mtop, repl);

  // attention on the top-24 rows: scores (LDS-tiled) -> softmax+PV partials
  {
    dim3 sgrid(Lq / JT, Bq * Hq);  // (8, 32)
    scores_kernel<<<sgrid, 256, 0, stream>>>(q, k, mtop, scg);
  }
  {
    dim3 pgrid(NCH, Bq * Hq * Uq);  // (8, 768)
    softmax_pv_partial<<<pgrid, 256, 0, stream>>>(scg, v, mtop, pmax, psum, pvp);
  }

  // cumsum context: tile sums -> supertile sums -> build (two-level prefix)
  tile_sum<<<Bq * NTILE, 128, 0, stream>>>(v, tsum);
  stile_sum<<<Bq * NSUP, 128, 0, stream>>>(tsum, stsum);
  build_context<<<Bq * NTILE, 128, 0, stream>>>(v, tsum, stsum, repl, pmax,
                                                psum, pvp, ctxh);

  // output projection (plain bf16, 128x128 tiles, async LDS staging)
  {
    dim3 ggrid(64, 4);
    gemm_bf16<<<ggrid, 256, 0, stream>>>(ctxh, Woh, bo, out);
  }
}

// Round 14
// 276.441 us; speedup vs baseline: 1.1118x; 1.0018x over previous
//
#include <hip/hip_runtime.h>
#include <hip/hip_bf16.h>
#include <math.h>

#define Bq 4
#define Lq 2048
#define Dq 512
#define Hq 8
#define DKq 64
#define Uq 24
#define TSCAN 16
#define NTILE (Lq / TSCAN)   // 128
#define NSUP 16              // supertiles (8 tiles each)
#define JCH 256              // softmax j-chunk
#define NCH (Lq / JCH)       // 8
#define TKCH 8               // top-k chunks per bh

typedef unsigned short ushort_t;
typedef unsigned long long u64;
typedef __attribute__((ext_vector_type(8))) short bfrag8;   // 8 bf16 (4 VGPRs)
typedef __attribute__((ext_vector_type(4))) float facc4;    // MFMA accumulator

__device__ inline ushort_t bf16_rne(float f) {
  unsigned u = __float_as_uint(f);
  u += 0x7FFF + ((u >> 16) & 1);
  return (ushort_t)(u >> 16);
}
__device__ inline float bf16f(ushort_t h) {
  return __uint_as_float(((unsigned)h) << 16);
}
// monotone float -> uint map (no NaNs in inputs)
__device__ inline unsigned fkey(float f) {
  unsigned u = __float_as_uint(f);
  return (u & 0x80000000u) ? ~u : (u | 0x80000000u);
}
// async global->LDS, 16B per lane (lds dest = wave base + lane*16)
__device__ __forceinline__ void gl2lds16(const void* g, void* l) {
  __builtin_amdgcn_global_load_lds(
      (const __attribute__((address_space(1))) unsigned*)g,
      (__attribute__((address_space(3))) unsigned*)l, 16, 0, 0);
}

// ---------------------------------------------------------------------------
// activations: one launch. y=0: q->hi/lo, y=1: k->hi/lo, y=2: v->hi
// ---------------------------------------------------------------------------
__global__ __launch_bounds__(256) void cast_all(
    const float* __restrict__ xq, const float* __restrict__ xk,
    const float* __restrict__ xv, ushort_t* __restrict__ qh,
    ushort_t* __restrict__ ql, ushort_t* __restrict__ kh,
    ushort_t* __restrict__ kl, ushort_t* __restrict__ vh) {
  int z = blockIdx.y;
  const float* x = z == 0 ? xq : (z == 1 ? xk : xv);
  ushort_t* hi = z == 0 ? qh : (z == 1 ? kh : vh);
  ushort_t* lo = z == 0 ? ql : kl;  // unused for z==2
  int t = blockIdx.x * 256 + threadIdx.x;
  float4 v = *(const float4*)&x[(size_t)t * 4];
  ushort_t h0 = bf16_rne(v.x), h1 = bf16_rne(v.y), h2 = bf16_rne(v.z),
           h3 = bf16_rne(v.w);
  ushort4 hh = {h0, h1, h2, h3};
  *(ushort4*)&hi[(size_t)t * 4] = hh;
  if (z < 2) {
    ushort4 ll = {bf16_rne(v.x - bf16f(h0)), bf16_rne(v.y - bf16f(h1)),
                  bf16_rne(v.z - bf16f(h2)), bf16_rne(v.w - bf16f(h3))};
    *(ushort4*)&lo[(size_t)t * 4] = ll;
  }
}

// ---------------------------------------------------------------------------
// All 4 weights: fp32 [k][n] -> transposed bf16 hi/lo [n][k] (one launch)
// ---------------------------------------------------------------------------
__global__ __launch_bounds__(256) void transpose_cast4(
    const float* __restrict__ W0, const float* __restrict__ W1,
    const float* __restrict__ W2, const float* __restrict__ W3,
    ushort_t* __restrict__ T0h, ushort_t* __restrict__ T0l,
    ushort_t* __restrict__ T1h, ushort_t* __restrict__ T1l,
    ushort_t* __restrict__ T2h, ushort_t* __restrict__ T3h) {
  __shared__ float tile[32][33];
  int z = blockIdx.z;
  const float* W = z == 0 ? W0 : (z == 1 ? W1 : (z == 2 ? W2 : W3));
  ushort_t* Th = z == 0 ? T0h : (z == 1 ? T1h : (z == 2 ? T2h : T3h));
  ushort_t* Tl = z == 0 ? T0l : (z == 1 ? T1l : nullptr);
  int k0 = blockIdx.x * 32, n0 = blockIdx.y * 32;
  int tx = threadIdx.x & 31, ty = threadIdx.x >> 5;  // ty 0..7
  for (int r = ty; r < 32; r += 8)
    tile[tx][r] = W[(size_t)(k0 + r) * 512 + n0 + tx];
  __syncthreads();
  for (int r = ty; r < 32; r += 8) {
    float v = tile[r][tx];
    ushort_t h = bf16_rne(v);
    Th[(size_t)(n0 + r) * 512 + k0 + tx] = h;
    if (Tl) Tl[(size_t)(n0 + r) * 512 + k0 + tx] = bf16_rne(v - bf16f(h));
  }
}

// ---------------------------------------------------------------------------
// Fused Q/K/V projection GEMM, 128x128 tile, 4 waves x (64x64).
// z=0: Q (split-bf16), z=1: K (split), z=2: V (plain hi).
// XOR-swizzled LDS chunks: phys chunk pc of row holds logical chunk
// pc ^ ((row>>1)&3) -> fragment b128 reads are 2-way max (conflict-free).
// global_load_lds dest stays lane*16 contiguous (only source is permuted).
// ---------------------------------------------------------------------------
__global__ __launch_bounds__(256) void gemm_qkv(
    const ushort_t* __restrict__ Aqh, const ushort_t* __restrict__ Aql,
    const ushort_t* __restrict__ Akh, const ushort_t* __restrict__ Akl,
    const ushort_t* __restrict__ Avh,
    const ushort_t* __restrict__ Wqh, const ushort_t* __restrict__ Wql,
    const ushort_t* __restrict__ Wkh, const ushort_t* __restrict__ Wkl,
    const ushort_t* __restrict__ Wvh,
    const float* __restrict__ bq, const float* __restrict__ bk,
    const float* __restrict__ bv,
    float* __restrict__ qo, float* __restrict__ ko, float* __restrict__ vo) {
  __shared__ ushort_t Ash[128][32], Asl[128][32];  // 8 KB each
  __shared__ ushort_t Bsh[128][32], Bsl[128][32];
  int which = blockIdx.z;
  const ushort_t* Ah = which == 0 ? Aqh : (which == 1 ? Akh : Avh);
  const ushort_t* Al = which == 0 ? Aql : Akl;  // unused for V
  const ushort_t* Bh = which == 0 ? Wqh : (which == 1 ? Wkh : Wvh);
  const ushort_t* Bl = which == 0 ? Wql : Wkl;
  const float* bias = which == 0 ? bq : (which == 1 ? bk : bv);
  float* C = which == 0 ? qo : (which == 1 ? ko : vo);
  const bool split = which < 2;

  int bm = blockIdx.x, bn = blockIdx.y;
  int tid = threadIdx.x;
  int wave = tid >> 6, lane = tid & 63;
  int wm = (wave & 1) * 64, wn = (wave >> 1) * 64;
  int quad = lane >> 4, lm = lane & 15;
  int srow = tid >> 2;                                  // staging row (p=0)
  int slc = (((tid & 3) ^ ((tid >> 3) & 3))) * 8;       // logical chunk (global src)
  int sphys = (tid & 3) * 8;                            // physical chunk (LDS dest)
  int rsw = (quad ^ ((lm >> 1) & 3)) * 8;               // fragment read chunk
  facc4 acc[4][4] = {};

  for (int k0 = 0; k0 < 512; k0 += 32) {
#pragma unroll
    for (int p = 0; p < 2; ++p) {
      int row = srow + p * 64;
      size_t ga = (size_t)(bm * 128 + row) * 512 + k0 + slc;
      size_t gb = (size_t)(bn * 128 + row) * 512 + k0 + slc;
      gl2lds16(&Ah[ga], &Ash[row][sphys]);
      gl2lds16(&Bh[gb], &Bsh[row][sphys]);
      if (split) {
        gl2lds16(&Al[ga], &Asl[row][sphys]);
        gl2lds16(&Bl[gb], &Bsl[row][sphys]);
      }
    }
    __syncthreads();
    bfrag8 afh[4], afl[4], bfh[4], bfl[4];
#pragma unroll
    for (int mt = 0; mt < 4; ++mt) {
      afh[mt] = *(bfrag8*)&Ash[wm + mt * 16 + lm][rsw];
      if (split) afl[mt] = *(bfrag8*)&Asl[wm + mt * 16 + lm][rsw];
    }
#pragma unroll
    for (int nt = 0; nt < 4; ++nt) {
      bfh[nt] = *(bfrag8*)&Bsh[wn + nt * 16 + lm][rsw];
      if (split) bfl[nt] = *(bfrag8*)&Bsl[wn + nt * 16 + lm][rsw];
    }
#pragma unroll
    for (int mt = 0; mt < 4; ++mt)
#pragma unroll
      for (int nt = 0; nt < 4; ++nt) {
        facc4 a = acc[mt][nt];
        a = __builtin_amdgcn_mfma_f32_16x16x32_bf16(afh[mt], bfh[nt], a, 0, 0, 0);
        if (split) {
          a = __builtin_amdgcn_mfma_f32_16x16x32_bf16(afl[mt], bfh[nt], a, 0, 0, 0);
          a = __builtin_amdgcn_mfma_f32_16x16x32_bf16(afh[mt], bfl[nt], a, 0, 0, 0);
        }
        acc[mt][nt] = a;
      }
    __syncthreads();
  }
#pragma unroll
  for (int mt = 0; mt < 4; ++mt)
#pragma unroll
    for (int nt = 0; nt < 4; ++nt) {
      int col = bn * 128 + wn + nt * 16 + lm;
      float bv2 = bias[col];
#pragma unroll
      for (int r = 0; r < 4; ++r) {
        int row = bm * 128 + wm + mt * 16 + quad * 4 + r;
        C[(size_t)row * 512 + col] = acc[mt][nt][r] + bv2;
      }
    }
}

// ---------------------------------------------------------------------------
// bf16 MFMA GEMM (hi only): out projection, 128x128 tile, swizzled LDS
// ---------------------------------------------------------------------------
__global__ __launch_bounds__(256) void gemm_bf16(
    const ushort_t* __restrict__ A, const ushort_t* __restrict__ Bt,
    const float* __restrict__ bias, float* __restrict__ C) {
  __shared__ ushort_t As[128][32];
  __shared__ ushort_t Bs[128][32];
  int bm = blockIdx.x, bn = blockIdx.y;
  int tid = threadIdx.x;
  int wave = tid >> 6, lane = tid & 63;
  int wm = (wave & 1) * 64, wn = (wave >> 1) * 64;
  int quad = lane >> 4, lm = lane & 15;
  int srow = tid >> 2;
  int slc = (((tid & 3) ^ ((tid >> 3) & 3))) * 8;
  int sphys = (tid & 3) * 8;
  int rsw = (quad ^ ((lm >> 1) & 3)) * 8;
  facc4 acc[4][4] = {};

  for (int k0 = 0; k0 < 512; k0 += 32) {
#pragma unroll
    for (int p = 0; p < 2; ++p) {
      int row = srow + p * 64;
      gl2lds16(&A[(size_t)(bm * 128 + row) * 512 + k0 + slc], &As[row][sphys]);
      gl2lds16(&Bt[(size_t)(bn * 128 + row) * 512 + k0 + slc], &Bs[row][sphys]);
    }
    __syncthreads();
    bfrag8 af[4], bf[4];
#pragma unroll
    for (int mt = 0; mt < 4; ++mt)
      af[mt] = *(bfrag8*)&As[wm + mt * 16 + lm][rsw];
#pragma unroll
    for (int nt = 0; nt < 4; ++nt)
      bf[nt] = *(bfrag8*)&Bs[wn + nt * 16 + lm][rsw];
#pragma unroll
    for (int mt = 0; mt < 4; ++mt)
#pragma unroll
      for (int nt = 0; nt < 4; ++nt)
        acc[mt][nt] = __builtin_amdgcn_mfma_f32_16x16x32_bf16(
            af[mt], bf[nt], acc[mt][nt], 0, 0, 0);
    __syncthreads();
  }
#pragma unroll
  for (int mt = 0; mt < 4; ++mt)
#pragma unroll
    for (int nt = 0; nt < 4; ++nt) {
      int col = bn * 128 + wn + nt * 16 + lm;
      float bv = bias[col];
#pragma unroll
      for (int r = 0; r < 4; ++r) {
        int row = bm * 128 + wm + mt * 16 + quad * 4 + r;
        C[(size_t)row * 512 + col] = acc[mt][nt][r] + bv;
      }
    }
}

// ---------------------------------------------------------------------------
// m[b,h,l] = max_s(q.k_sample) - sum_s(q.k_sample)/L  (bit-exact selection)
// ---------------------------------------------------------------------------
__global__ __launch_bounds__(256) void compute_m(
    const float* __restrict__ q, const float* __restrict__ k,
    const int* __restrict__ idxs, float* __restrict__ m) {
  int wave = threadIdx.x >> 6, lane = threadIdx.x & 63;
  int lq = lane >> 4, dq = lane & 15;
  int slot = (blockIdx.x * 4 + wave) * 4 + lq;  // (b,h,l) flat
  int l = slot & (Lq - 1);
  int bh = slot >> 11;
  int h = bh & (Hq - 1), b = bh >> 3;
  float4 qv = *(const float4*)&q[((size_t)b * Lq + l) * Dq + h * DKq + dq * 4];
  const float* kb = &k[(size_t)b * Lq * Dq + h * DKq + dq * 4];
  const int* ib = &idxs[l * Uq];
  float mx = -INFINITY, sm = 0.f;
#pragma unroll
  for (int s = 0; s < Uq; ++s) {
    int j = ib[s];
    float4 kv = *(const float4*)&kb[(size_t)j * Dq];
    float p = qv.x * kv.x + qv.y * kv.y + qv.z * kv.z + qv.w * kv.w;
    p += __shfl_xor(p, 1, 64);
    p += __shfl_xor(p, 2, 64);
    p += __shfl_xor(p, 4, 64);
    p += __shfl_xor(p, 8, 64);
    mx = fmaxf(mx, p);
    sm += p;
  }
  if (dq == 0) m[slot] = mx - sm * (1.0f / Lq);
}

// ---------------------------------------------------------------------------
// top-24 per (b,h), two-stage bitonic on packed keys.
// stage2 also builds repl[] (indices already in LDS).
// ---------------------------------------------------------------------------
__device__ inline void bitonic256_desc(u64* s, int tid) {
  for (int k = 2; k <= 256; k <<= 1) {
    for (int j = k >> 1; j > 0; j >>= 1) {
      int p = tid ^ j;
      u64 mine = s[tid], other = s[p];
      u64 mx = mine > other ? mine : other;
      u64 mn = mine > other ? other : mine;
      bool dir = (tid & k) == 0;   // descending block
      bool lower = tid < p;
      u64 res = dir ? (lower ? mx : mn) : (lower ? mn : mx);
      __syncthreads();
      s[tid] = res;
      __syncthreads();
    }
  }
}

__global__ __launch_bounds__(256) void topk_stage1(
    const float* __restrict__ m, u64* __restrict__ cand) {
  __shared__ u64 s[256];
  int bh = blockIdx.x >> 3;      // 0..31
  int ch = blockIdx.x & 7;       // chunk 0..7
  int tid = threadIdx.x;
  int gidx = ch * 256 + tid;
  float v = m[(size_t)bh * Lq + gidx];
  s[tid] = ((u64)fkey(v) << 32) | (u64)(Lq - 1 - gidx);
  __syncthreads();
  bitonic256_desc(s, tid);
  if (tid < Uq) cand[((size_t)bh * TKCH + ch) * Uq + tid] = s[tid];
}

__global__ __launch_bounds__(256) void topk_stage2(
    const u64* __restrict__ cand, int* __restrict__ mtop,
    int* __restrict__ repl) {
  __shared__ u64 s[256];
  __shared__ int mt[Uq];
  int bh = blockIdx.x;
  int tid = threadIdx.x;
  s[tid] = (tid < TKCH * Uq) ? cand[(size_t)bh * TKCH * Uq + tid] : 0ull;
  __syncthreads();
  bitonic256_desc(s, tid);
  if (tid < Uq) {
    int idx = Lq - 1 - (int)(s[tid] & 0xFFFFFFFFull);
    mtop[bh * Uq + tid] = idx;
    mt[tid] = idx;
  }
  __syncthreads();
  for (int l = tid; l < Lq; l += 256) {
    int u = -1;
#pragma unroll
    for (int t = 0; t < Uq; ++t)
      if (mt[t] == l) u = t;
    repl[(size_t)bh * Lq + l] = u;
  }
}

// ---------------------------------------------------------------------------
// scores[bh][u][j] = (q[b,i0[u],h,:] . k[b,j,h,:]) / sqrt(D)
// LDS-staged, register-tiled 3u x 2j, k reused across all 24 u's.
// ---------------------------------------------------------------------------
#define JT 256
#define JS 64

__global__ __launch_bounds__(256) void scores_kernel(
    const float* __restrict__ q, const float* __restrict__ k,
    const int* __restrict__ mtop, float* __restrict__ scg) {
  __shared__ float qs[Uq][DKq + 1];
  __shared__ float ks[JS][DKq + 1];
  __shared__ int i0s[Uq];
  int bh = blockIdx.y;
  int jt = blockIdx.x;
  int h = bh & (Hq - 1);
  int b = bh >> 3;
  int tid = threadIdx.x;
  if (tid < Uq) i0s[tid] = mtop[bh * Uq + tid];
  __syncthreads();
  for (int s = tid; s < Uq * 16; s += 256) {
    int u = s >> 4, qd = (s & 15) * 4;
    float4 t = *(const float4*)&q[((size_t)b * Lq + i0s[u]) * Dq + h * DKq + qd];
    qs[u][qd] = t.x; qs[u][qd + 1] = t.y; qs[u][qd + 2] = t.z; qs[u][qd + 3] = t.w;
  }
  int jp = tid & 31;
  int ug = tid >> 5;
  const float scale = 0.044194173824159216f;  // 1/sqrt(512)
  for (int sub = 0; sub < JT / JS; ++sub) {
    int jbase = jt * JT + sub * JS;
    __syncthreads();
    for (int s = tid; s < JS * 16; s += 256) {
      int j = s >> 4, qd = (s & 15) * 4;
      float4 t = *(const float4*)&k[((size_t)b * Lq + jbase + j) * Dq + h * DKq + qd];
      ks[j][qd] = t.x; ks[j][qd + 1] = t.y; ks[j][qd + 2] = t.z; ks[j][qd + 3] = t.w;
    }
    __syncthreads();
    float acc[3][2] = {};
    int j0 = jp * 2, j1 = j0 + 1;
#pragma unroll 8
    for (int d = 0; d < DKq; ++d) {
      float k0 = ks[j0][d], k1 = ks[j1][d];
#pragma unroll
      for (int uu = 0; uu < 3; ++uu) {
        float qv = qs[ug * 3 + uu][d];
        acc[uu][0] += qv * k0;
        acc[uu][1] += qv * k1;
      }
    }
#pragma unroll
    for (int uu = 0; uu < 3; ++uu) {
      int u = ug * 3 + uu;
      scg[((size_t)(bh * Uq + u)) * Lq + jbase + j0] = acc[uu][0] * scale;
      scg[((size_t)(bh * Uq + u)) * Lq + jbase + j1] = acc[uu][1] * scale;
    }
  }
}

// ---------------------------------------------------------------------------
// softmax+PV partials over j-chunks of 256 (reads scg)
// ---------------------------------------------------------------------------
__global__ __launch_bounds__(256) void softmax_pv_partial(
    const float* __restrict__ scg, const float* __restrict__ v,
    const int* __restrict__ mtop, float* __restrict__ pmax,
    float* __restrict__ psum, float* __restrict__ pvp) {
  int blk = blockIdx.y;  // bh*U + u
  int jc = blockIdx.x;
  int bh = blk / Uq;
  int h = bh & (Hq - 1);
  int b = bh >> 3;
  int n = mtop[blk] + 1;   // causal bound
  int j0 = jc * JCH;
  if (j0 >= n) return;
  int cnt = min(JCH, n - j0);
  int tid = threadIdx.x, wave = tid >> 6, lane = tid & 63;
  __shared__ float es[JCH];
  __shared__ float red[4][DKq];
  __shared__ float rr[4];

  const float* row = &scg[(size_t)blk * Lq + j0];
  float mx = (tid < cnt) ? row[tid] : -INFINITY;
#pragma unroll
  for (int off = 32; off; off >>= 1) mx = fmaxf(mx, __shfl_xor(mx, off, 64));
  if (lane == 0) rr[wave] = mx;
  __syncthreads();
  mx = fmaxf(fmaxf(rr[0], rr[1]), fmaxf(rr[2], rr[3]));
  __syncthreads();

  float e = (tid < cnt) ? __expf(row[tid] - mx) : 0.f;
  es[tid] = e;
  float sm = e;
#pragma unroll
  for (int off = 32; off; off >>= 1) sm += __shfl_xor(sm, off, 64);
  if (lane == 0) rr[wave] = sm;
  __syncthreads();

  float acc = 0.f;
  const float* vb = &v[((size_t)b * Lq + j0) * Dq + h * DKq + lane];
  int jlo = wave * 64;
  int jhi = min(jlo + 64, cnt);
#pragma unroll 4
  for (int j = jlo; j < jhi; ++j) acc += es[j] * vb[(size_t)j * Dq];
  red[wave][lane] = acc;
  __syncthreads();
  if (wave == 0) {
    if (lane == 0) {
      pmax[blk * NCH + jc] = mx;
      psum[blk * NCH + jc] = rr[0] + rr[1] + rr[2] + rr[3];
    }
    pvp[((size_t)blk * NCH + jc) * DKq + lane] =
        red[0][lane] + red[1][lane] + red[2][lane] + red[3][lane];
  }
}

// ---------------------------------------------------------------------------
// cumsum over L: tile sums (16 rows), supertile sums (8 tiles), then
// build_context with two-level prefix (<=22 loads), inline combine, bf16 out.
// ---------------------------------------------------------------------------
__global__ __launch_bounds__(128) void tile_sum(const float* __restrict__ v,
                                                float* __restrict__ tsum) {
  int blk = blockIdx.x;  // b*NTILE + tile
  int tile = blk & (NTILE - 1);
  int b = blk >> 7;
  int d4 = threadIdx.x;  // 0..127 (float4 column slice)
  float4 s = {0.f, 0.f, 0.f, 0.f};
  const float* base = &v[((size_t)b * Lq + tile * TSCAN) * Dq + d4 * 4];
#pragma unroll
  for (int r = 0; r < TSCAN; ++r) {
    float4 x = *(const float4*)&base[(size_t)r * Dq];
    s.x += x.x; s.y += x.y; s.z += x.z; s.w += x.w;
  }
  *(float4*)&tsum[((size_t)b * NTILE + tile) * Dq + d4 * 4] = s;
}

__global__ __launch_bounds__(128) void stile_sum(
    const float* __restrict__ tsum, float* __restrict__ stsum) {
  int blk = blockIdx.x;  // b*NSUP + s
  int s = blk & (NSUP - 1);
  int b = blk >> 4;
  int d4 = threadIdx.x;
  float4 acc = {0.f, 0.f, 0.f, 0.f};
  const float* tb = &tsum[((size_t)b * NTILE + s * 8) * Dq + d4 * 4];
#pragma unroll
  for (int i = 0; i < 8; ++i) {
    float4 t = *(const float4*)&tb[(size_t)i * Dq];
    acc.x += t.x; acc.y += t.y; acc.z += t.z; acc.w += t.w;
  }
  *(float4*)&stsum[((size_t)b * NSUP + s) * Dq + d4 * 4] = acc;
}

__global__ __launch_bounds__(128) void build_context(
    const float* __restrict__ v, const float* __restrict__ tsum,
    const float* __restrict__ stsum, const int* __restrict__ repl,
    const float* __restrict__ pmax, const float* __restrict__ psum,
    const float* __restrict__ pvp, ushort_t* __restrict__ ctxh) {
  int blk = blockIdx.x;  // b*NTILE + tile
  int tile = blk & (NTILE - 1);
  int b = blk >> 7;
  int d4 = threadIdx.x;          // float4 column slice
  int h = d4 >> 4;               // (d4*4)>>6
  // two-level exclusive prefix: full supertiles + remaining tiles
  int sup = tile >> 3;
  float4 run = {0.f, 0.f, 0.f, 0.f};
  const float* sb = &stsum[(size_t)b * NSUP * Dq + d4 * 4];
  for (int s = 0; s < sup; ++s) {
    float4 t = *(const float4*)&sb[(size_t)s * Dq];
    run.x += t.x; run.y += t.y; run.z += t.z; run.w += t.w;
  }
  const float* tb = &tsum[((size_t)b * NTILE + sup * 8) * Dq + d4 * 4];
  int rem = tile & 7;
  for (int i = 0; i < rem; ++i) {
    float4 t = *(const float4*)&tb[(size_t)i * Dq];
    run.x += t.x; run.y += t.y; run.z += t.z; run.w += t.w;
  }
  const int* replb = &repl[(size_t)(b * Hq + h) * Lq + tile * TSCAN];
  const float* vb = &v[((size_t)b * Lq + tile * TSCAN) * Dq + d4 * 4];
  ushort_t* cb = &ctxh[((size_t)b * Lq + tile * TSCAN) * Dq + d4 * 4];
#pragma unroll
  for (int r = 0; r < TSCAN; ++r) {
    float4 x = *(const float4*)&vb[(size_t)r * Dq];
    run.x += x.x; run.y += x.y; run.z += x.z; run.w += x.w;
    int u = replb[r];
    float4 val = run;
    if (u >= 0) {
      // inline softmax combine: l == mtop[u]  =>  n = l+1
      int l = tile * TSCAN + r;
      int blku = (b * Hq + h) * Uq + u;
      int nc = (l + JCH) / JCH;  // ceil((l+1)/JCH)
      float gmax = -INFINITY;
      for (int c = 0; c < nc; ++c) gmax = fmaxf(gmax, pmax[blku * NCH + c]);
      float tot = 0.f;
      float4 acc = {0.f, 0.f, 0.f, 0.f};
      for (int c = 0; c < nc; ++c) {
        float wgt = __expf(pmax[blku * NCH + c] - gmax);
        tot += psum[blku * NCH + c] * wgt;
        float4 pv = *(const float4*)&pvp[((size_t)blku * NCH + c) * DKq +
                                         (d4 & 15) * 4];
        acc.x += pv.x * wgt; acc.y += pv.y * wgt;
        acc.z += pv.z * wgt; acc.w += pv.w * wgt;
      }
      float inv = 1.0f / tot;
      val.x = acc.x * inv; val.y = acc.y * inv;
      val.z = acc.z * inv; val.w = acc.w * inv;
    }
    ushort4 o = {bf16_rne(val.x), bf16_rne(val.y), bf16_rne(val.z),
                 bf16_rne(val.w)};
    *(ushort4*)&cb[(size_t)r * Dq] = o;
  }
}

// ---------------------------------------------------------------------------
extern "C" void kernel_launch(void* const* d_in, const int* in_sizes, int n_in,
                              void* d_out, int out_size, void* d_ws,
                              size_t ws_size, hipStream_t stream) {
  const float* queries = (const float*)d_in[0];
  const float* keys    = (const float*)d_in[1];
  const float* values  = (const float*)d_in[2];
  const int*   idxs    = (const int*)d_in[3];
  const float* Wq = (const float*)d_in[4];
  const float* bq = (const float*)d_in[5];
  const float* Wk = (const float*)d_in[6];
  const float* bk = (const float*)d_in[7];
  const float* Wv = (const float*)d_in[8];
  const float* bv = (const float*)d_in[9];
  const float* Wo = (const float*)d_in[10];
  const float* bo = (const float*)d_in[11];
  float* out = (float*)d_out;

  const size_t BLD = (size_t)Bq * Lq * Dq;  // 4,194,304
  char* w = (char*)d_ws;
  float* q    = (float*)w; w += BLD * 4;
  float* k    = (float*)w; w += BLD * 4;
  float* v    = (float*)w; w += BLD * 4;
  float* scg  = (float*)w; w += (size_t)Bq * Hq * Uq * Lq * 4;  // 6.3 MB
  float* m    = (float*)w; w += (size_t)Bq * Hq * Lq * 4;
  float* tsum = (float*)w; w += (size_t)Bq * NTILE * Dq * 4;
  float* stsum= (float*)w; w += (size_t)Bq * NSUP * Dq * 4;
  int* mtop   = (int*)w;   w += Bq * Hq * Uq * 4;
  int* repl   = (int*)w;   w += (size_t)Bq * Hq * Lq * 4;
  float* pmax = (float*)w; w += (size_t)Bq * Hq * Uq * NCH * 4;
  float* psum = (float*)w; w += (size_t)Bq * Hq * Uq * NCH * 4;
  float* pvp  = (float*)w; w += (size_t)Bq * Hq * Uq * NCH * DKq * 4;
  u64* cand   = (u64*)w;   w += (size_t)Bq * Hq * TKCH * Uq * 8;
  ushort_t* ctxh = (ushort_t*)w; w += BLD * 2;  // bf16 context
  ushort_t* Aqh = (ushort_t*)w; w += BLD * 2;   // pre-cast activations
  ushort_t* Aql = (ushort_t*)w; w += BLD * 2;
  ushort_t* Akh = (ushort_t*)w; w += BLD * 2;
  ushort_t* Akl = (ushort_t*)w; w += BLD * 2;
  ushort_t* Avh = (ushort_t*)w; w += BLD * 2;
  const size_t WSZ = 512 * 512;
  ushort_t* Wqh = (ushort_t*)w; w += WSZ * 2;
  ushort_t* Wql = (ushort_t*)w; w += WSZ * 2;
  ushort_t* Wkh = (ushort_t*)w; w += WSZ * 2;
  ushort_t* Wkl = (ushort_t*)w; w += WSZ * 2;
  ushort_t* Wvh = (ushort_t*)w; w += WSZ * 2;
  ushort_t* Woh = (ushort_t*)w; w += WSZ * 2;

  // weights: transpose + hi/lo cast, one launch
  {
    dim3 tgrid(16, 16, 4);
    transpose_cast4<<<tgrid, 256, 0, stream>>>(Wq, Wk, Wv, Wo, Wqh, Wql, Wkh,
                                               Wkl, Wvh, Woh);
  }

  // pre-cast activations, one launch (Q,K hi/lo; V hi)
  {
    dim3 cgrid(BLD / 4 / 256, 3);  // (4096, 3)
    cast_all<<<cgrid, 256, 0, stream>>>(queries, keys, values, Aqh, Aql, Akh,
                                        Akl, Avh);
  }

  // fused Q/K/V projections (128x128 tiles, async LDS staging, swizzled)
  {
    dim3 ggrid(64, 4, 3);  // M=8192/128, N=512/128, z = Q/K/V
    gemm_qkv<<<ggrid, 256, 0, stream>>>(Aqh, Aql, Akh, Akl, Avh, Wqh, Wql,
                                        Wkh, Wkl, Wvh, bq, bk, bv, q, k, v);
  }

  // sparsity metric + top-k (two-stage bitonic; stage2 also builds repl)
  compute_m<<<(Bq * Hq * Lq) / 16, 256, 0, stream>>>(q, k, idxs, m);
  topk_stage1<<<Bq * Hq * TKCH, 256, 0, stream>>>(m, cand);
  topk_stage2<<<Bq * Hq, 256, 0, stream>>>(cand, mtop, repl);

  // attention on the top-24 rows: scores (LDS-tiled) -> softmax+PV partials
  {
    dim3 sgrid(Lq / JT, Bq * Hq);  // (8, 32)
    scores_kernel<<<sgrid, 256, 0, stream>>>(q, k, mtop, scg);
  }
  {
    dim3 pgrid(NCH, Bq * Hq * Uq);  // (8, 768)
    softmax_pv_partial<<<pgrid, 256, 0, stream>>>(scg, v, mtop, pmax, psum, pvp);
  }

  // cumsum context: tile sums -> supertile sums -> build (two-level prefix)
  tile_sum<<<Bq * NTILE, 128, 0, stream>>>(v, tsum);
  stile_sum<<<Bq * NSUP, 128, 0, stream>>>(tsum, stsum);
  build_context<<<Bq * NTILE, 128, 0, stream>>>(v, tsum, stsum, repl, pmax,
                                                psum, pvp, ctxh);

  // output projection (plain bf16, 128x128 tiles, swizzled LDS)
  {
    dim3 ggrid(64, 4);
    gemm_bf16<<<ggrid, 256, 0, stream>>>(ctxh, Woh, bo, out);
  }
}